// Round 2
// baseline (4073.527 us; speedup 1.0000x reference)
//
#include <hip/hip_runtime.h>
#include <math.h>

#define BB 512
#define SS 128
#define EE 300
#define HH 300
#define FCIN 1800
#define LLI 2

__device__ __forceinline__ float fast_tanh(float x){
    float ax = fabsf(x);
    float t = __expf(-2.f*ax);
    float r = (1.f - t) / (1.f + t);
    return copysignf(r, x);
}

// ---------------- embedding gather + valid mask + mean(s) ----------------
// grid: (bc, 2), block 256. Block handles full (b,which): gathers rows,
// accumulates seq-mean into res seg 0.
__global__ void embed_mean_kernel(const int* __restrict__ seq1, const int* __restrict__ seq2,
                                  const float* __restrict__ emb,
                                  float* __restrict__ s1, float* __restrict__ s2,
                                  float* __restrict__ v1, float* __restrict__ v2,
                                  float* __restrict__ res, int b0){
    int bl = blockIdx.x, which = blockIdx.y;
    const int* seq = which ? seq2 : seq1;
    float* sd = which ? s2 : s1;
    float* vd = which ? v2 : v1;
    int tid = threadIdx.x;
    int e1 = tid, e2 = tid + 256;
    float acc1 = 0.f, acc2 = 0.f;
    for (int s = 0; s < SS; s++){
        int token = seq[(size_t)(b0+bl)*SS + s];
        if (tid == 0) vd[bl*SS + s] = (token != 0) ? 1.f : 0.f;
        const float* er = emb + (size_t)token * EE;
        float* orow = sd + ((size_t)bl*SS + s) * EE;
        if (e1 < EE){ float v = er[e1]; orow[e1] = v; acc1 += v; }
        if (e2 < EE){ float v = er[e2]; orow[e2] = v; acc2 += v; }
    }
    float* rr = res + (size_t)(b0+bl)*FCIN + which*900;
    if (e1 < EE) rr[e1] = acc1 * (1.f/SS);
    if (e2 < EE) rr[e2] = acc2 * (1.f/SS);
}

// ---------------- match score (norms fused; MODE1: + w1/w2 + pool fused) ----
// grid: bc blocks, block 256 (16x16 threads, 8x8 micro-tile)
#define KK 10
template<int MODE>
__global__ __launch_bounds__(256) void cross_kernel(
    const float* __restrict__ xa, const float* __restrict__ xb,
    const float* __restrict__ va, const float* __restrict__ vb,
    float* __restrict__ Aout, float* __restrict__ su1, float* __restrict__ su2)
{
    __shared__ float As[KK][132];
    __shared__ float Bs[KK][132];
    __shared__ float nA[SS], nB[SS], vA[SS], vB[SS];
    __shared__ float wr[SS], wc[SS];
    __shared__ float colred[16][132];

    int bl = blockIdx.x;
    const float* xar = xa + (size_t)bl*SS*EE;
    const float* xbr = xb + (size_t)bl*SS*EE;
    int tid = threadIdx.x;
    int wave = tid >> 6, lane = tid & 63;

    // --- fused masked norms (and v into LDS) ---
    for (int row = wave; row < SS; row += 4){
        const float* ra = xar + (size_t)row*EE;
        const float* rb = xbr + (size_t)row*EE;
        float a = 0.f, b = 0.f;
        for (int e = lane; e < EE; e += 64){
            float t = ra[e]; a += t*t;
            float u = rb[e]; b += u*u;
        }
        #pragma unroll
        for (int o = 32; o > 0; o >>= 1){ a += __shfl_down(a, o); b += __shfl_down(b, o); }
        if (lane == 0){
            float mva = va[bl*SS + row], mvb = vb[bl*SS + row];
            nA[row] = a * mva; nB[row] = b * mvb;
            vA[row] = mva;     vB[row] = mvb;
        }
    }
    __syncthreads();

    int tx = tid & 15, ty = tid >> 4;
    int i0 = ty*8, j0 = tx*8;
    float acc[8][8] = {};
    for (int k0 = 0; k0 < EE; k0 += KK){
        #pragma unroll
        for (int u = 0; u < 5; u++){
            int idx = tid + u*256;           // 0..1279
            int i = idx / KK, k = idx - i*KK;
            As[k][i] = xar[i*EE + k0 + k] * vA[i];
            Bs[k][i] = xbr[i*EE + k0 + k] * vB[i];
        }
        __syncthreads();
        #pragma unroll
        for (int k = 0; k < KK; k++){
            float a[8], b[8];
            #pragma unroll
            for (int r = 0; r < 8; r++) a[r] = As[k][i0+r];
            #pragma unroll
            for (int c = 0; c < 8; c++) b[c] = Bs[k][j0+c];
            #pragma unroll
            for (int r = 0; r < 8; r++)
                #pragma unroll
                for (int c = 0; c < 8; c++)
                    acc[r][c] = fmaf(a[r], b[c], acc[r][c]);
        }
        __syncthreads();
    }
    float nr[8], nc[8];
    #pragma unroll
    for (int r = 0; r < 8; r++) nr[r] = nA[i0+r];
    #pragma unroll
    for (int c = 0; c < 8; c++) nc[c] = nB[j0+c];

    float aval[8][8];
    #pragma unroll
    for (int r = 0; r < 8; r++)
        #pragma unroll
        for (int c = 0; c < 8; c++){
            float d2 = nr[r] + nc[c] - 2.f*acc[r][c];
            float d = sqrtf(fmaxf(d2, 0.f));
            aval[r][c] = 1.f / (1.f + d);
        }

    if constexpr (MODE == 0){
        float* Ar = Aout + (size_t)bl*SS*SS;
        #pragma unroll
        for (int r = 0; r < 8; r++)
            #pragma unroll
            for (int c = 0; c < 8; c++)
                Ar[(i0+r)*SS + j0+c] = aval[r][c];
    } else {
        // row sums (over j) -> wr ; col sums (over i) -> wc   (in LDS)
        float rowp[8], colp[8];
        #pragma unroll
        for (int r = 0; r < 8; r++){
            float s = 0.f;
            #pragma unroll
            for (int c = 0; c < 8; c++) s += aval[r][c];
            rowp[r] = s;
        }
        #pragma unroll
        for (int c = 0; c < 8; c++){
            float s = 0.f;
            #pragma unroll
            for (int r = 0; r < 8; r++) s += aval[r][c];
            colp[c] = s;
        }
        #pragma unroll
        for (int m = 1; m < 16; m <<= 1)
            #pragma unroll
            for (int r = 0; r < 8; r++) rowp[r] += __shfl_xor(rowp[r], m);
        if (tx == 0){
            #pragma unroll
            for (int r = 0; r < 8; r++) wr[i0+r] = rowp[r];
        }
        #pragma unroll
        for (int c = 0; c < 8; c++) colred[ty][j0+c] = colp[c];
        __syncthreads();
        if (tid < SS){
            float s = 0.f;
            #pragma unroll
            for (int g = 0; g < 16; g++) s += colred[g][tid];
            wc[tid] = s;
        }
        __syncthreads();

        // --- fused attention pool: s += avg3(o * w) ---
        #pragma unroll
        for (int which = 0; which < 2; which++){
            const float* ob = which ? xbr : xar;
            const float* wv = which ? wc : wr;
            float* sb = (which ? su2 : su1) + (size_t)bl*SS*EE;
            for (int idx = tid; idx < SS*EE; idx += 256){
                int row = idx / EE, e = idx - row*EE;
                float a = ob[row*EE + e] * wv[row];
                if (row > 0)      a += ob[(row-1)*EE + e] * wv[row-1];
                if (row < SS-1)   a += ob[(row+1)*EE + e] * wv[row+1];
                sb[row*EE + e] += a * (1.f/3.f);
            }
        }
    }
}

// ---------------- f1 = A @ W, f2 = A^T @ W ----------------
// grid: (bc, 10, 2)  y = mtile*5 + etile, z = which; block 256, 64x64 tile
#define FKK 16
__global__ __launch_bounds__(256) void f_kernel(const float* __restrict__ Abuf,
                                                const float* __restrict__ Wl,
                                                float* __restrict__ f1, float* __restrict__ f2){
    __shared__ float At[FKK][68];
    __shared__ float Wt[FKK][68];
    int bl = blockIdx.x;
    int m = blockIdx.y / 5, et = blockIdx.y - m*5;
    int which = blockIdx.z;
    const float* Ab = Abuf + (size_t)bl*SS*SS;
    int i0g = m*64, e0g = et*64;
    int tid = threadIdx.x, tx = tid & 15, ty = tid >> 4;
    float acc[4][4] = {};
    for (int k0 = 0; k0 < SS; k0 += FKK){
        if (which == 0){
            int i = tid >> 2;
            int kb = (tid & 3) * 4;
            #pragma unroll
            for (int u = 0; u < 4; u++){
                int k = kb + u;
                At[k][i] = Ab[(i0g+i)*SS + k0 + k];
            }
        } else {
            int i = tid & 63; int kb = tid >> 6;
            #pragma unroll
            for (int u = 0; u < 4; u++){
                int k = kb + u*4;
                At[k][i] = Ab[(k0+k)*SS + i0g + i];
            }
        }
        {
            int e = tid & 63; int kb = tid >> 6;
            int ge = e0g + e;
            #pragma unroll
            for (int u = 0; u < 4; u++){
                int k = kb + u*4;
                Wt[k][e] = (ge < EE) ? Wl[(k0+k)*EE + ge] : 0.f;
            }
        }
        __syncthreads();
        #pragma unroll
        for (int k = 0; k < FKK; k++){
            float av[4], wv[4];
            #pragma unroll
            for (int r = 0; r < 4; r++) av[r] = At[k][ty*4+r];
            #pragma unroll
            for (int c = 0; c < 4; c++) wv[c] = Wt[k][tx*4+c];
            #pragma unroll
            for (int r = 0; r < 4; r++)
                #pragma unroll
                for (int c = 0; c < 4; c++)
                    acc[r][c] = fmaf(av[r], wv[c], acc[r][c]);
        }
        __syncthreads();
    }
    float* fd = which ? f2 : f1;
    #pragma unroll
    for (int r = 0; r < 4; r++){
        int gi = i0g + ty*4 + r;
        #pragma unroll
        for (int c = 0; c < 4; c++){
            int ge = e0g + tx*4 + c;
            if (ge < EE) fd[(size_t)bl*SS*EE + gi*EE + ge] = acc[r][c];
        }
    }
}

// ---------------- conv(3x3,2ch) + tanh + mean(o) fused ----------------
// grid: (bc, 2), block 256. Direct global loads (no LDS staging); block
// covers full (b,which) so the seq-mean reduces intra-block into res.
__global__ __launch_bounds__(256) void conv_fused_kernel(
    const float* __restrict__ s1, const float* __restrict__ s2,
    const float* __restrict__ f1, const float* __restrict__ f2,
    const float* __restrict__ cw, const float* __restrict__ cb,
    float* __restrict__ o1, float* __restrict__ o2,
    float* __restrict__ res, int b0, int seg){
    int bl = blockIdx.x, which = blockIdx.y;
    const float* ca = (which ? s2 : s1) + (size_t)bl*SS*EE;
    const float* cf = (which ? f2 : f1) + (size_t)bl*SS*EE;
    float* od = (which ? o2 : o1) + (size_t)bl*SS*EE;
    float w[2][3][3];
    #pragma unroll
    for (int c = 0; c < 2; c++)
        #pragma unroll
        for (int dy = 0; dy < 3; dy++)
            #pragma unroll
            for (int dx = 0; dx < 3; dx++)
                w[c][dy][dx] = cw[c*9 + dy*3 + dx];
    float bias = cb[0];

    int tid = threadIdx.x;
    int ec = tid & 31, rg = tid >> 5;      // 32 e-chunks x 8 row-groups
    int e0 = ec * 10;                       // covers 0..319 (>=300)
    float msum[10];
    #pragma unroll
    for (int j = 0; j < 10; j++) msum[j] = 0.f;

    for (int pass = 0; pass < 16; pass++){
        int r = rg + pass*8;                // output row
        float acc[10];
        #pragma unroll
        for (int j = 0; j < 10; j++) acc[j] = bias;
        #pragma unroll
        for (int c = 0; c < 2; c++){
            const float* src = c ? cf : ca;
            #pragma unroll
            for (int dy = 0; dy < 3; dy++){
                int gr = r + dy - 1;
                if (gr < 0 || gr >= SS) continue;
                const float* row = src + (size_t)gr*EE;
                float x[12];
                #pragma unroll
                for (int t = 0; t < 12; t++){
                    int ge = e0 + t - 1;
                    x[t] = (ge >= 0 && ge < EE) ? row[ge] : 0.f;
                }
                #pragma unroll
                for (int j = 0; j < 10; j++)
                    acc[j] = fmaf(w[c][dy][0], x[j],
                              fmaf(w[c][dy][1], x[j+1],
                               fmaf(w[c][dy][2], x[j+2], acc[j])));
            }
        }
        #pragma unroll
        for (int j = 0; j < 10; j++){
            if (e0 + j < EE){
                float t = fast_tanh(acc[j]);
                od[(size_t)r*EE + e0 + j] = t;
                msum[j] += t;
            }
        }
    }
    // reduce mean across row-groups
    __shared__ float red[8][320];
    #pragma unroll
    for (int j = 0; j < 10; j++) red[rg][e0+j] = msum[j];
    __syncthreads();
    float* rr = res + (size_t)(b0+bl)*FCIN + which*900 + seg*300;
    for (int e = tid; e < EE; e += 256){
        float s = 0.f;
        #pragma unroll
        for (int g = 0; g < 8; g++) s += red[g][e];
        rr[e] = s * (1.f/SS);
    }
}

// ---------------- fc1: [512,1800] @ [1800,300]^T ----------------
#define CKK 12
__global__ __launch_bounds__(256) void fc1_kernel(const float* __restrict__ res,
                                                  const float* __restrict__ fw,
                                                  const float* __restrict__ fb,
                                                  float* __restrict__ h){
    __shared__ float Xt[CKK][68];
    __shared__ float Wt[CKK][68];
    int bt = blockIdx.x, jt = blockIdx.y;
    int tid = threadIdx.x, tx = tid & 15, ty = tid >> 4;
    int b0l = bt*64, j0 = jt*64;
    float acc[4][4] = {};
    for (int k0 = 0; k0 < FCIN; k0 += CKK){
        #pragma unroll
        for (int u = 0; u < 3; u++){
            int idx = tid + u*256;     // < 768
            int a = idx / CKK, k = idx - a*CKK;
            Xt[k][a] = res[(size_t)(b0l+a)*FCIN + k0 + k];
            int gj = j0 + a;
            Wt[k][a] = (gj < HH) ? fw[(size_t)gj*FCIN + k0 + k] : 0.f;
        }
        __syncthreads();
        #pragma unroll
        for (int k = 0; k < CKK; k++){
            float xv[4], wv[4];
            #pragma unroll
            for (int r = 0; r < 4; r++) xv[r] = Xt[k][ty*4+r];
            #pragma unroll
            for (int c = 0; c < 4; c++) wv[c] = Wt[k][tx*4+c];
            #pragma unroll
            for (int r = 0; r < 4; r++)
                #pragma unroll
                for (int c = 0; c < 4; c++)
                    acc[r][c] = fmaf(xv[r], wv[c], acc[r][c]);
        }
        __syncthreads();
    }
    #pragma unroll
    for (int r = 0; r < 4; r++){
        int gb = b0l + ty*4 + r;
        #pragma unroll
        for (int c = 0; c < 4; c++){
            int gj = j0 + tx*4 + c;
            if (gj < HH) h[(size_t)gb*HH + gj] = acc[r][c] + fb[gj];
        }
    }
}

// ---------------- layernorm + relu + fc2 + softmax ----------------
__global__ void head_kernel(const float* __restrict__ h, const float* __restrict__ g,
                            const float* __restrict__ be, const float* __restrict__ f2w,
                            const float* __restrict__ f2b, float* __restrict__ out){
    int b = blockIdx.x, tid = threadIdx.x;
    __shared__ float arr[HH];
    __shared__ float s_s[4], s_q[4], r0[4], r1[4];
    float x0 = (tid < HH) ? h[(size_t)b*HH + tid] : 0.f;
    float x1 = (tid + 256 < HH) ? h[(size_t)b*HH + tid + 256] : 0.f;
    float s = x0 + x1, sq = x0*x0 + x1*x1;
    #pragma unroll
    for (int o = 32; o > 0; o >>= 1){ s += __shfl_down(s, o); sq += __shfl_down(sq, o); }
    int wv = tid >> 6, ln = tid & 63;
    if (ln == 0){ s_s[wv] = s; s_q[wv] = sq; }
    __syncthreads();
    s  = s_s[0] + s_s[1] + s_s[2] + s_s[3];
    sq = s_q[0] + s_q[1] + s_q[2] + s_q[3];
    float mean = s / HH;
    float var = sq / HH - mean*mean;
    float inv = rsqrtf(var + 1e-5f);
    if (tid < HH)       arr[tid]     = fmaxf((x0 - mean)*inv*g[tid]     + be[tid],     0.f);
    if (tid + 256 < HH) arr[tid+256] = fmaxf((x1 - mean)*inv*g[tid+256] + be[tid+256], 0.f);
    __syncthreads();
    float p0 = 0.f, p1 = 0.f;
    for (int j = tid; j < HH; j += 256){ float hv = arr[j]; p0 += hv*f2w[j]; p1 += hv*f2w[HH+j]; }
    #pragma unroll
    for (int o = 32; o > 0; o >>= 1){ p0 += __shfl_down(p0, o); p1 += __shfl_down(p1, o); }
    if (ln == 0){ r0[wv] = p0; r1[wv] = p1; }
    __syncthreads();
    if (tid == 0){
        float o0 = r0[0]+r0[1]+r0[2]+r0[3] + f2b[0];
        float o1 = r1[0]+r1[1]+r1[2]+r1[3] + f2b[1];
        out[b*2+0] = o0; out[b*2+1] = o1;
        float m = fmaxf(o0, o1);
        float e0 = __expf(o0 - m), e1 = __expf(o1 - m);
        float den = e0 + e1;
        out[BB*2 + b*2+0] = e0/den;
        out[BB*2 + b*2+1] = e1/den;
    }
}

extern "C" void kernel_launch(void* const* d_in, const int* in_sizes, int n_in,
                              void* d_out, int out_size, void* d_ws, size_t ws_size,
                              hipStream_t stream){
    const int*   seq1   = (const int*)d_in[0];
    const int*   seq2   = (const int*)d_in[1];
    const float* emb    = (const float*)d_in[2];
    const float* W      = (const float*)d_in[3];
    const float* conv_w = (const float*)d_in[4];
    const float* conv_b = (const float*)d_in[5];
    const float* fc1_w  = (const float*)d_in[6];
    const float* fc1_b  = (const float*)d_in[7];
    const float* ln_g   = (const float*)d_in[8];
    const float* ln_b   = (const float*)d_in[9];
    const float* fc2_w  = (const float*)d_in[10];
    const float* fc2_b  = (const float*)d_in[11];
    float* out = (float*)d_out;

    float* ws = (float*)d_ws;
    size_t fixedf = (size_t)BB*FCIN + (size_t)BB*HH;
    size_t perb   = (size_t)6*SS*EE + (size_t)SS*SS + 2*SS;
    size_t avail  = ws_size / 4;
    long long bcl = (long long)((avail > fixedf ? avail - fixedf : 0) / perb);
    int BC = (int)(bcl < 1 ? 1 : (bcl > BB ? BB : bcl));

    float* res = ws;
    float* hb  = res + (size_t)BB*FCIN;
    float* s1  = hb  + (size_t)BB*HH;
    float* s2  = s1  + (size_t)BC*SS*EE;
    float* f1b = s2  + (size_t)BC*SS*EE;
    float* f2b = f1b + (size_t)BC*SS*EE;
    float* o1  = f2b + (size_t)BC*SS*EE;
    float* o2  = o1  + (size_t)BC*SS*EE;
    float* Ab  = o2  + (size_t)BC*SS*EE;
    float* v1  = Ab  + (size_t)BC*SS*SS;
    float* v2  = v1 + (size_t)BC*SS;

    for (int b0 = 0; b0 < BB; b0 += BC){
        int bc = (BB - b0 < BC) ? (BB - b0) : BC;
        embed_mean_kernel<<<dim3(bc, 2), 256, 0, stream>>>(seq1, seq2, emb, s1, s2, v1, v2, res, b0);
        for (int it = 0; it < LLI; it++){
            cross_kernel<0><<<bc, 256, 0, stream>>>(s1, s2, v1, v2, Ab, nullptr, nullptr);
            f_kernel<<<dim3(bc, 10, 2), 256, 0, stream>>>(Ab, W + (size_t)it*SS*EE, f1b, f2b);
            conv_fused_kernel<<<dim3(bc, 2), 256, 0, stream>>>(s1, s2, f1b, f2b,
                                                               conv_w + it*18, conv_b + it,
                                                               o1, o2, res, b0, it+1);
            cross_kernel<1><<<bc, 256, 0, stream>>>(o1, o2, v1, v2, nullptr, s1, s2);
        }
    }
    fc1_kernel<<<dim3(8, 5), 256, 0, stream>>>(res, fc1_w, fc1_b, hb);
    head_kernel<<<BB, 256, 0, stream>>>(hb, ln_g, ln_b, fc2_w, fc2_b, out);
}

// Round 3
// 3342.147 us; speedup vs baseline: 1.2188x; 1.2188x over previous
//
#include <hip/hip_runtime.h>
#include <math.h>

#define BB 512
#define SS 128
#define EE 300
#define HH 300
#define FCIN 1800
#define LLI 2

__device__ __forceinline__ float fast_tanh(float x){
    float ax = fabsf(x);
    float t = __expf(-2.f*ax);
    float r = (1.f - t) / (1.f + t);
    return copysignf(r, x);
}

// ---------------- embedding gather + valid mask + mean(s) ----------------
// grid: (bc, 2), block 256
__global__ void embed_mean_kernel(const int* __restrict__ seq1, const int* __restrict__ seq2,
                                  const float* __restrict__ emb,
                                  float* __restrict__ s1, float* __restrict__ s2,
                                  float* __restrict__ v1, float* __restrict__ v2,
                                  float* __restrict__ res, int b0){
    int bl = blockIdx.x, which = blockIdx.y;
    const int* seq = which ? seq2 : seq1;
    float* sd = which ? s2 : s1;
    float* vd = which ? v2 : v1;
    int tid = threadIdx.x;
    int e1 = tid, e2 = tid + 256;
    float acc1 = 0.f, acc2 = 0.f;
    for (int s = 0; s < SS; s++){
        int token = seq[(size_t)(b0+bl)*SS + s];
        if (tid == 0) vd[bl*SS + s] = (token != 0) ? 1.f : 0.f;
        const float* er = emb + (size_t)token * EE;
        float* orow = sd + ((size_t)bl*SS + s) * EE;
        if (e1 < EE){ float v = er[e1]; orow[e1] = v; acc1 += v; }
        if (e2 < EE){ float v = er[e2]; orow[e2] = v; acc2 += v; }
    }
    float* rr = res + (size_t)(b0+bl)*FCIN + which*900;
    if (e1 < EE) rr[e1] = acc1 * (1.f/SS);
    if (e2 < EE) rr[e2] = acc2 * (1.f/SS);
}

// ---------------- match score (norms fused; MODE1: + w1/w2 + pool fused) ----
// grid: bc blocks, block 512 (16x32 threads, 8x4 micro-tile)
// __launch_bounds__(512,4): cap VGPR<=128 -> 2 blocks/CU -> 16 waves/CU
#define KK 10
template<int MODE>
__global__ __launch_bounds__(512, 4) void cross_kernel(
    const float* __restrict__ xa, const float* __restrict__ xb,
    const float* __restrict__ va, const float* __restrict__ vb,
    float* __restrict__ Aout, float* __restrict__ su1, float* __restrict__ su2)
{
    __shared__ float As[KK][132];
    __shared__ float Bs[KK][132];
    __shared__ float nA[SS], nB[SS], vA[SS], vB[SS];
    __shared__ float wr[SS], wc[SS];
    __shared__ float colred[8][132];

    int bl = blockIdx.x;
    const float* xar = xa + (size_t)bl*SS*EE;
    const float* xbr = xb + (size_t)bl*SS*EE;
    int tid = threadIdx.x;
    int wave = tid >> 6, lane = tid & 63;

    // --- fused masked norms (and v into LDS) ---
    for (int row = wave; row < SS; row += 8){
        const float* ra = xar + (size_t)row*EE;
        const float* rb = xbr + (size_t)row*EE;
        float a = 0.f, b = 0.f;
        for (int e = lane; e < EE; e += 64){
            float t = ra[e]; a += t*t;
            float u = rb[e]; b += u*u;
        }
        #pragma unroll
        for (int o = 32; o > 0; o >>= 1){ a += __shfl_down(a, o); b += __shfl_down(b, o); }
        if (lane == 0){
            float mva = va[bl*SS + row], mvb = vb[bl*SS + row];
            nA[row] = a * mva; nB[row] = b * mvb;
            vA[row] = mva;     vB[row] = mvb;
        }
    }
    __syncthreads();

    int tx = tid & 31, ty = tid >> 5;      // 32 x 16
    int i0 = ty*8, j0 = tx*4;
    float acc[8][4] = {};
    for (int k0 = 0; k0 < EE; k0 += KK){
        #pragma unroll
        for (int u = 0; u < 3; u++){
            int idx = tid + u*512;           // 0..1535, need <1280
            if (idx < SS*KK){
                int i = idx / KK, k = idx - i*KK;
                As[k][i] = xar[i*EE + k0 + k] * vA[i];
                Bs[k][i] = xbr[i*EE + k0 + k] * vB[i];
            }
        }
        __syncthreads();
        #pragma unroll
        for (int k = 0; k < KK; k++){
            float4 a0 = *(const float4*)&As[k][i0];
            float4 a1 = *(const float4*)&As[k][i0+4];
            float4 b0 = *(const float4*)&Bs[k][j0];
            float a[8] = {a0.x,a0.y,a0.z,a0.w,a1.x,a1.y,a1.z,a1.w};
            float b[4] = {b0.x,b0.y,b0.z,b0.w};
            #pragma unroll
            for (int r = 0; r < 8; r++)
                #pragma unroll
                for (int c = 0; c < 4; c++)
                    acc[r][c] = fmaf(a[r], b[c], acc[r][c]);
        }
        __syncthreads();
    }
    float nr[8], nc[4];
    #pragma unroll
    for (int r = 0; r < 8; r++) nr[r] = nA[i0+r];
    #pragma unroll
    for (int c = 0; c < 4; c++) nc[c] = nB[j0+c];

    float aval[8][4];
    #pragma unroll
    for (int r = 0; r < 8; r++)
        #pragma unroll
        for (int c = 0; c < 4; c++){
            float d2 = nr[r] + nc[c] - 2.f*acc[r][c];
            float d = sqrtf(fmaxf(d2, 0.f));
            aval[r][c] = 1.f / (1.f + d);
        }

    if constexpr (MODE == 0){
        float* Ar = Aout + (size_t)bl*SS*SS;
        #pragma unroll
        for (int r = 0; r < 8; r++){
            float4 v4 = make_float4(aval[r][0], aval[r][1], aval[r][2], aval[r][3]);
            *(float4*)&Ar[(i0+r)*SS + j0] = v4;
        }
    } else {
        // row sums (over j) -> wr ; col sums (over i) -> wc
        float rowp[8], colp[4];
        #pragma unroll
        for (int r = 0; r < 8; r++){
            float s = 0.f;
            #pragma unroll
            for (int c = 0; c < 4; c++) s += aval[r][c];
            rowp[r] = s;
        }
        #pragma unroll
        for (int c = 0; c < 4; c++){
            float s = 0.f;
            #pragma unroll
            for (int r = 0; r < 8; r++) s += aval[r][c];
            colp[c] = s;
        }
        // reduce rowp across tx (lanes 0-31 and 32-63 are distinct ty)
        #pragma unroll
        for (int m = 1; m < 32; m <<= 1)
            #pragma unroll
            for (int r = 0; r < 8; r++) rowp[r] += __shfl_xor(rowp[r], m);
        if (tx == 0){
            #pragma unroll
            for (int r = 0; r < 8; r++) wr[i0+r] = rowp[r];
        }
        // reduce colp across ty: first pair-reduce within wave (ty, ty+1)
        #pragma unroll
        for (int c = 0; c < 4; c++) colp[c] += __shfl_xor(colp[c], 32);
        if (lane < 32){
            float4 v4 = make_float4(colp[0], colp[1], colp[2], colp[3]);
            *(float4*)&colred[wave][j0] = v4;
        }
        __syncthreads();
        if (tid < SS){
            float s = 0.f;
            #pragma unroll
            for (int g = 0; g < 8; g++) s += colred[g][tid];
            wc[tid] = s;
        }
        __syncthreads();

        // --- fused attention pool: s += avg3(o * w) ---
        #pragma unroll
        for (int which = 0; which < 2; which++){
            const float* ob = which ? xbr : xar;
            const float* wv = which ? wc : wr;
            float* sb = (which ? su2 : su1) + (size_t)bl*SS*EE;
            for (int idx = tid; idx < SS*EE; idx += 512){
                int row = idx / EE, e = idx - row*EE;
                float a = ob[row*EE + e] * wv[row];
                if (row > 0)      a += ob[(row-1)*EE + e] * wv[row-1];
                if (row < SS-1)   a += ob[(row+1)*EE + e] * wv[row+1];
                sb[row*EE + e] += a * (1.f/3.f);
            }
        }
    }
}

// ---------------- f1 = A @ W, f2 = A^T @ W ----------------
// grid: (bc, 10, 2)  y = mtile*5 + etile, z = which; block 256, 64x64 tile
#define FKK 16
__global__ __launch_bounds__(256) void f_kernel(const float* __restrict__ Abuf,
                                                const float* __restrict__ Wl,
                                                float* __restrict__ f1, float* __restrict__ f2){
    __shared__ float At[FKK][68];
    __shared__ float Wt[FKK][68];
    int bl = blockIdx.x;
    int m = blockIdx.y / 5, et = blockIdx.y - m*5;
    int which = blockIdx.z;
    const float* Ab = Abuf + (size_t)bl*SS*SS;
    int i0g = m*64, e0g = et*64;
    int tid = threadIdx.x, tx = tid & 15, ty = tid >> 4;
    float acc[4][4] = {};
    for (int k0 = 0; k0 < SS; k0 += FKK){
        if (which == 0){
            int i = tid >> 2;
            int kb = (tid & 3) * 4;
            #pragma unroll
            for (int u = 0; u < 4; u++){
                int k = kb + u;
                At[k][i] = Ab[(i0g+i)*SS + k0 + k];
            }
        } else {
            int i = tid & 63; int kb = tid >> 6;
            #pragma unroll
            for (int u = 0; u < 4; u++){
                int k = kb + u*4;
                At[k][i] = Ab[(k0+k)*SS + i0g + i];
            }
        }
        {
            int e = tid & 63; int kb = tid >> 6;
            int ge = e0g + e;
            #pragma unroll
            for (int u = 0; u < 4; u++){
                int k = kb + u*4;
                Wt[k][e] = (ge < EE) ? Wl[(k0+k)*EE + ge] : 0.f;
            }
        }
        __syncthreads();
        #pragma unroll
        for (int k = 0; k < FKK; k++){
            float av[4], wv[4];
            #pragma unroll
            for (int r = 0; r < 4; r++) av[r] = At[k][ty*4+r];
            #pragma unroll
            for (int c = 0; c < 4; c++) wv[c] = Wt[k][tx*4+c];
            #pragma unroll
            for (int r = 0; r < 4; r++)
                #pragma unroll
                for (int c = 0; c < 4; c++)
                    acc[r][c] = fmaf(av[r], wv[c], acc[r][c]);
        }
        __syncthreads();
    }
    float* fd = which ? f2 : f1;
    #pragma unroll
    for (int r = 0; r < 4; r++){
        int gi = i0g + ty*4 + r;
        #pragma unroll
        for (int c = 0; c < 4; c++){
            int ge = e0g + tx*4 + c;
            if (ge < EE) fd[(size_t)bl*SS*EE + gi*EE + ge] = acc[r][c];
        }
    }
}

// ---------------- conv(3x3,2ch) + tanh + mean(o) fused ----------------
// grid: (bc, 2), block 256
__global__ __launch_bounds__(256) void conv_fused_kernel(
    const float* __restrict__ s1, const float* __restrict__ s2,
    const float* __restrict__ f1, const float* __restrict__ f2,
    const float* __restrict__ cw, const float* __restrict__ cb,
    float* __restrict__ o1, float* __restrict__ o2,
    float* __restrict__ res, int b0, int seg){
    int bl = blockIdx.x, which = blockIdx.y;
    const float* ca = (which ? s2 : s1) + (size_t)bl*SS*EE;
    const float* cf = (which ? f2 : f1) + (size_t)bl*SS*EE;
    float* od = (which ? o2 : o1) + (size_t)bl*SS*EE;
    float w[2][3][3];
    #pragma unroll
    for (int c = 0; c < 2; c++)
        #pragma unroll
        for (int dy = 0; dy < 3; dy++)
            #pragma unroll
            for (int dx = 0; dx < 3; dx++)
                w[c][dy][dx] = cw[c*9 + dy*3 + dx];
    float bias = cb[0];

    int tid = threadIdx.x;
    int ec = tid & 31, rg = tid >> 5;      // 32 e-chunks x 8 row-groups
    int e0 = ec * 10;                       // covers 0..319 (>=300)
    float msum[10];
    #pragma unroll
    for (int j = 0; j < 10; j++) msum[j] = 0.f;

    for (int pass = 0; pass < 16; pass++){
        int r = rg + pass*8;                // output row
        float acc[10];
        #pragma unroll
        for (int j = 0; j < 10; j++) acc[j] = bias;
        #pragma unroll
        for (int c = 0; c < 2; c++){
            const float* src = c ? cf : ca;
            #pragma unroll
            for (int dy = 0; dy < 3; dy++){
                int gr = r + dy - 1;
                if (gr < 0 || gr >= SS) continue;
                const float* row = src + (size_t)gr*EE;
                float x[12];
                #pragma unroll
                for (int t = 0; t < 12; t++){
                    int ge = e0 + t - 1;
                    x[t] = (ge >= 0 && ge < EE) ? row[ge] : 0.f;
                }
                #pragma unroll
                for (int j = 0; j < 10; j++)
                    acc[j] = fmaf(w[c][dy][0], x[j],
                              fmaf(w[c][dy][1], x[j+1],
                               fmaf(w[c][dy][2], x[j+2], acc[j])));
            }
        }
        #pragma unroll
        for (int j = 0; j < 10; j++){
            if (e0 + j < EE){
                float t = fast_tanh(acc[j]);
                od[(size_t)r*EE + e0 + j] = t;
                msum[j] += t;
            }
        }
    }
    // reduce mean across row-groups
    __shared__ float red[8][320];
    #pragma unroll
    for (int j = 0; j < 10; j++) red[rg][e0+j] = msum[j];
    __syncthreads();
    float* rr = res + (size_t)(b0+bl)*FCIN + which*900 + seg*300;
    for (int e = tid; e < EE; e += 256){
        float s = 0.f;
        #pragma unroll
        for (int g = 0; g < 8; g++) s += red[g][e];
        rr[e] = s * (1.f/SS);
    }
}

// ---------------- fc1: [512,1800] @ [1800,300]^T ----------------
#define CKK 12
__global__ __launch_bounds__(256) void fc1_kernel(const float* __restrict__ res,
                                                  const float* __restrict__ fw,
                                                  const float* __restrict__ fb,
                                                  float* __restrict__ h){
    __shared__ float Xt[CKK][68];
    __shared__ float Wt[CKK][68];
    int bt = blockIdx.x, jt = blockIdx.y;
    int tid = threadIdx.x, tx = tid & 15, ty = tid >> 4;
    int b0l = bt*64, j0 = jt*64;
    float acc[4][4] = {};
    for (int k0 = 0; k0 < FCIN; k0 += CKK){
        #pragma unroll
        for (int u = 0; u < 3; u++){
            int idx = tid + u*256;     // < 768
            int a = idx / CKK, k = idx - a*CKK;
            Xt[k][a] = res[(size_t)(b0l+a)*FCIN + k0 + k];
            int gj = j0 + a;
            Wt[k][a] = (gj < HH) ? fw[(size_t)gj*FCIN + k0 + k] : 0.f;
        }
        __syncthreads();
        #pragma unroll
        for (int k = 0; k < CKK; k++){
            float xv[4], wv[4];
            #pragma unroll
            for (int r = 0; r < 4; r++) xv[r] = Xt[k][ty*4+r];
            #pragma unroll
            for (int c = 0; c < 4; c++) wv[c] = Wt[k][tx*4+c];
            #pragma unroll
            for (int r = 0; r < 4; r++)
                #pragma unroll
                for (int c = 0; c < 4; c++)
                    acc[r][c] = fmaf(xv[r], wv[c], acc[r][c]);
        }
        __syncthreads();
    }
    #pragma unroll
    for (int r = 0; r < 4; r++){
        int gb = b0l + ty*4 + r;
        #pragma unroll
        for (int c = 0; c < 4; c++){
            int gj = j0 + tx*4 + c;
            if (gj < HH) h[(size_t)gb*HH + gj] = acc[r][c] + fb[gj];
        }
    }
}

// ---------------- layernorm + relu + fc2 + softmax ----------------
__global__ void head_kernel(const float* __restrict__ h, const float* __restrict__ g,
                            const float* __restrict__ be, const float* __restrict__ f2w,
                            const float* __restrict__ f2b, float* __restrict__ out){
    int b = blockIdx.x, tid = threadIdx.x;
    __shared__ float arr[HH];
    __shared__ float s_s[4], s_q[4], r0[4], r1[4];
    float x0 = (tid < HH) ? h[(size_t)b*HH + tid] : 0.f;
    float x1 = (tid + 256 < HH) ? h[(size_t)b*HH + tid + 256] : 0.f;
    float s = x0 + x1, sq = x0*x0 + x1*x1;
    #pragma unroll
    for (int o = 32; o > 0; o >>= 1){ s += __shfl_down(s, o); sq += __shfl_down(sq, o); }
    int wv = tid >> 6, ln = tid & 63;
    if (ln == 0){ s_s[wv] = s; s_q[wv] = sq; }
    __syncthreads();
    s  = s_s[0] + s_s[1] + s_s[2] + s_s[3];
    sq = s_q[0] + s_q[1] + s_q[2] + s_q[3];
    float mean = s / HH;
    float var = sq / HH - mean*mean;
    float inv = rsqrtf(var + 1e-5f);
    if (tid < HH)       arr[tid]     = fmaxf((x0 - mean)*inv*g[tid]     + be[tid],     0.f);
    if (tid + 256 < HH) arr[tid+256] = fmaxf((x1 - mean)*inv*g[tid+256] + be[tid+256], 0.f);
    __syncthreads();
    float p0 = 0.f, p1 = 0.f;
    for (int j = tid; j < HH; j += 256){ float hv = arr[j]; p0 += hv*f2w[j]; p1 += hv*f2w[HH+j]; }
    #pragma unroll
    for (int o = 32; o > 0; o >>= 1){ p0 += __shfl_down(p0, o); p1 += __shfl_down(p1, o); }
    if (ln == 0){ r0[wv] = p0; r1[wv] = p1; }
    __syncthreads();
    if (tid == 0){
        float o0 = r0[0]+r0[1]+r0[2]+r0[3] + f2b[0];
        float o1 = r1[0]+r1[1]+r1[2]+r1[3] + f2b[1];
        out[b*2+0] = o0; out[b*2+1] = o1;
        float m = fmaxf(o0, o1);
        float e0 = __expf(o0 - m), e1 = __expf(o1 - m);
        float den = e0 + e1;
        out[BB*2 + b*2+0] = e0/den;
        out[BB*2 + b*2+1] = e1/den;
    }
}

extern "C" void kernel_launch(void* const* d_in, const int* in_sizes, int n_in,
                              void* d_out, int out_size, void* d_ws, size_t ws_size,
                              hipStream_t stream){
    const int*   seq1   = (const int*)d_in[0];
    const int*   seq2   = (const int*)d_in[1];
    const float* emb    = (const float*)d_in[2];
    const float* W      = (const float*)d_in[3];
    const float* conv_w = (const float*)d_in[4];
    const float* conv_b = (const float*)d_in[5];
    const float* fc1_w  = (const float*)d_in[6];
    const float* fc1_b  = (const float*)d_in[7];
    const float* ln_g   = (const float*)d_in[8];
    const float* ln_b   = (const float*)d_in[9];
    const float* fc2_w  = (const float*)d_in[10];
    const float* fc2_b  = (const float*)d_in[11];
    float* out = (float*)d_out;

    float* ws = (float*)d_ws;
    size_t fixedf = (size_t)BB*FCIN + (size_t)BB*HH;
    size_t perb   = (size_t)6*SS*EE + (size_t)SS*SS + 2*SS;
    size_t avail  = ws_size / 4;
    long long bcl = (long long)((avail > fixedf ? avail - fixedf : 0) / perb);
    int BC = (int)(bcl < 1 ? 1 : (bcl > BB ? BB : bcl));

    float* res = ws;
    float* hb  = res + (size_t)BB*FCIN;
    float* s1  = hb  + (size_t)BB*HH;
    float* s2  = s1  + (size_t)BC*SS*EE;
    float* f1b = s2  + (size_t)BC*SS*EE;
    float* f2b = f1b + (size_t)BC*SS*EE;
    float* o1  = f2b + (size_t)BC*SS*EE;
    float* o2  = o1  + (size_t)BC*SS*EE;
    float* Ab  = o2  + (size_t)BC*SS*EE;
    float* v1  = Ab  + (size_t)BC*SS*SS;
    float* v2  = v1 + (size_t)BC*SS;

    for (int b0 = 0; b0 < BB; b0 += BC){
        int bc = (BB - b0 < BC) ? (BB - b0) : BC;
        embed_mean_kernel<<<dim3(bc, 2), 256, 0, stream>>>(seq1, seq2, emb, s1, s2, v1, v2, res, b0);
        for (int it = 0; it < LLI; it++){
            cross_kernel<0><<<bc, 512, 0, stream>>>(s1, s2, v1, v2, Ab, nullptr, nullptr);
            f_kernel<<<dim3(bc, 10, 2), 256, 0, stream>>>(Ab, W + (size_t)it*SS*EE, f1b, f2b);
            conv_fused_kernel<<<dim3(bc, 2), 256, 0, stream>>>(s1, s2, f1b, f2b,
                                                               conv_w + it*18, conv_b + it,
                                                               o1, o2, res, b0, it+1);
            cross_kernel<1><<<bc, 512, 0, stream>>>(o1, o2, v1, v2, nullptr, s1, s2);
        }
    }
    fc1_kernel<<<dim3(8, 5), 256, 0, stream>>>(res, fc1_w, fc1_b, hb);
    head_kernel<<<BB, 256, 0, stream>>>(hb, ln_g, ln_b, fc2_w, fc2_b, out);
}

// Round 4
// 2980.961 us; speedup vs baseline: 1.3665x; 1.1212x over previous
//
#include <hip/hip_runtime.h>
#include <math.h>

#define BB 512
#define SS 128
#define EE 300
#define HH 300
#define FCIN 1800
#define LLI 2
#define KP 320          // padded K for fp16 GEMM operands

using half8 = __attribute__((ext_vector_type(8))) _Float16;
using f32x4 = __attribute__((ext_vector_type(4))) float;

__device__ __forceinline__ float fast_tanh(float x){
    float ax = fabsf(x);
    float t = __expf(-2.f*ax);
    float r = (1.f - t) / (1.f + t);
    return copysignf(r, x);
}

// ---------------- Wt build: Wt[it][e][j] = W[it][j][e], fp16, e zero-padded to 320
__global__ void wt_build_kernel(const float* __restrict__ W, _Float16* __restrict__ Wt){
    int idx = blockIdx.x*256 + threadIdx.x;      // 2*320*128 = 81920
    if (idx >= 2*KP*SS) return;
    int j = idx & 127;
    int e = (idx >> 7) % KP;
    int it = idx / (KP*SS);
    float v = (e < EE) ? W[(size_t)it*SS*EE + j*EE + e] : 0.f;
    Wt[idx] = (_Float16)v;
}

// ---------------- embedding gather + v + mean(s) + masked fp16 sm + norms ----
// grid: (bc, 2), block 256
__global__ void embed_mean_kernel(const int* __restrict__ seq1, const int* __restrict__ seq2,
                                  const float* __restrict__ emb,
                                  float* __restrict__ s1, float* __restrict__ s2,
                                  float* __restrict__ v1, float* __restrict__ v2,
                                  _Float16* __restrict__ sm1, _Float16* __restrict__ sm2,
                                  float* __restrict__ n1, float* __restrict__ n2,
                                  float* __restrict__ res, int b0){
    int bl = blockIdx.x, which = blockIdx.y;
    const int* seq = which ? seq2 : seq1;
    float* sd = which ? s2 : s1;
    float* vd = which ? v2 : v1;
    int tid = threadIdx.x;
    int e1 = tid, e2 = tid + 256;
    float acc1 = 0.f, acc2 = 0.f;
    for (int s = 0; s < SS; s++){
        int token = seq[(size_t)(b0+bl)*SS + s];
        if (tid == 0) vd[bl*SS + s] = (token != 0) ? 1.f : 0.f;
        const float* er = emb + (size_t)token * EE;
        float* orow = sd + ((size_t)bl*SS + s) * EE;
        if (e1 < EE){ float v = er[e1]; orow[e1] = v; acc1 += v; }
        if (e2 < EE){ float v = er[e2]; orow[e2] = v; acc2 += v; }
    }
    float* rr = res + (size_t)(b0+bl)*FCIN + which*900;
    if (e1 < EE) rr[e1] = acc1 * (1.f/SS);
    if (e2 < EE) rr[e2] = acc2 * (1.f/SS);
    __syncthreads();
    // phase 2: masked fp16 copy + row norms
    _Float16* smg = (which ? sm2 : sm1) + (size_t)bl*SS*KP;
    float* ng = (which ? n2 : n1) + bl*SS;
    int wv = tid >> 6, lane = tid & 63;
    for (int row = wv; row < SS; row += 4){
        int token = seq[(size_t)(b0+bl)*SS + row];
        float vr = (token != 0) ? 1.f : 0.f;
        const float* sr = sd + ((size_t)bl*SS + row) * EE;
        float acc = 0.f;
        for (int e = lane; e < KP; e += 64){
            if (e < EE){
                float sv = sr[e] * vr;
                smg[row*KP + e] = (_Float16)sv;
                acc += sv*sv;
            } else {
                smg[row*KP + e] = (_Float16)0.f;
            }
        }
        #pragma unroll
        for (int o = 32; o > 0; o >>= 1) acc += __shfl_down(acc, o);
        if (lane == 0) ng[row] = acc;
    }
}

// ---------------- MFMA cross: 128x128, K=320 fp16 ----------------
// MODE0: write A, At (fp16). MODE1: w1/w2 + pool + s/sm/n update.
// block 512 (8 waves); wave = 16 rows x 128 cols (8 c-frags)
template<int MODE>
__global__ __launch_bounds__(512, 4) void cross_mfma(
    const _Float16* __restrict__ smA, const _Float16* __restrict__ smB,
    const float* __restrict__ nAg, const float* __restrict__ nBg,
    _Float16* __restrict__ Ab16, _Float16* __restrict__ At16,
    const float* __restrict__ o1g, const float* __restrict__ o2g,
    float* __restrict__ s1g, float* __restrict__ s2g,
    _Float16* __restrict__ sm1g, _Float16* __restrict__ sm2g,
    float* __restrict__ n1g, float* __restrict__ n2g,
    const float* __restrict__ v1g, const float* __restrict__ v2g)
{
    __shared__ _Float16 As[128][40];     // pad 40: 2-way bank alias only
    __shared__ _Float16 Bs[128][40];
    __shared__ float nAl[128], nBl[128];
    __shared__ float wr[128], wc[128];
    __shared__ float colred[8][132];

    int bl = blockIdx.x;
    int tid = threadIdx.x;
    int w = tid >> 6, lane = tid & 63;
    int m = lane & 15, quad = lane >> 4;

    const _Float16* gA = smA + (size_t)bl*SS*KP;
    const _Float16* gB = smB + (size_t)bl*SS*KP;

    if (tid < 128) nAl[tid] = nAg[bl*SS + tid];
    else if (tid < 256) nBl[tid-128] = nBg[bl*SS + tid-128];

    f32x4 acc[8];
    #pragma unroll
    for (int c = 0; c < 8; c++) acc[c] = (f32x4){0.f,0.f,0.f,0.f};

    int srow = tid >> 2, skq = (tid & 3) * 8;
    int arow = w*16 + m;

    for (int kc = 0; kc < 10; kc++){
        __syncthreads();
        *(float4*)&As[srow][skq] = *(const float4*)(gA + srow*KP + kc*32 + skq);
        *(float4*)&Bs[srow][skq] = *(const float4*)(gB + srow*KP + kc*32 + skq);
        __syncthreads();
        half8 a = *(const half8*)&As[arow][quad*8];
        #pragma unroll
        for (int c = 0; c < 8; c++){
            half8 b = *(const half8*)&Bs[c*16 + m][quad*8];
            acc[c] = __builtin_amdgcn_mfma_f32_16x16x32_f16(a, b, acc[c], 0, 0, 0);
        }
    }

    int ibase = w*16 + quad*4;
    float aval[8][4];
    #pragma unroll
    for (int c = 0; c < 8; c++){
        float nc = nBl[c*16 + m];
        #pragma unroll
        for (int r = 0; r < 4; r++){
            float d2 = nAl[ibase+r] + nc - 2.f*acc[c][r];
            float d = sqrtf(fmaxf(d2, 0.f));
            aval[c][r] = 1.f / (1.f + d);
        }
    }

    if constexpr (MODE == 0){
        _Float16* Ao  = Ab16 + (size_t)bl*SS*SS;
        _Float16* Ato = At16 + (size_t)bl*SS*SS;
        #pragma unroll
        for (int c = 0; c < 8; c++){
            int j = c*16 + m;
            #pragma unroll
            for (int r = 0; r < 4; r++){
                int i = ibase + r;
                _Float16 hv = (_Float16)aval[c][r];
                Ao[i*SS + j]  = hv;
                Ato[j*SS + i] = hv;
            }
        }
    } else {
        // row sums -> wr[i]; col sums -> wc[j]
        float rp[4];
        #pragma unroll
        for (int r = 0; r < 4; r++){
            float s = 0.f;
            #pragma unroll
            for (int c = 0; c < 8; c++) s += aval[c][r];
            rp[r] = s;
        }
        #pragma unroll
        for (int mask = 1; mask < 16; mask <<= 1)
            #pragma unroll
            for (int r = 0; r < 4; r++) rp[r] += __shfl_xor(rp[r], mask);
        if (m == 0){
            #pragma unroll
            for (int r = 0; r < 4; r++) wr[ibase+r] = rp[r];
        }
        float cp[8];
        #pragma unroll
        for (int c = 0; c < 8; c++){
            float s = 0.f;
            #pragma unroll
            for (int r = 0; r < 4; r++) s += aval[c][r];
            cp[c] = s;
        }
        #pragma unroll
        for (int c = 0; c < 8; c++){
            cp[c] += __shfl_xor(cp[c], 16);
            cp[c] += __shfl_xor(cp[c], 32);
        }
        if (quad == 0){
            #pragma unroll
            for (int c = 0; c < 8; c++) colred[w][c*16 + m] = cp[c];
        }
        __syncthreads();
        if (tid < 128){
            float s = 0.f;
            #pragma unroll
            for (int g = 0; g < 8; g++) s += colred[g][tid];
            wc[tid] = s;
        }
        __syncthreads();

        // pool + residual + masked fp16 + norms. wave handles rows w*16..w*16+15
        #pragma unroll
        for (int which = 0; which < 2; which++){
            const float* og = (which ? o2g : o1g) + (size_t)bl*SS*EE;
            float* sg       = (which ? s2g : s1g) + (size_t)bl*SS*EE;
            _Float16* smg   = (which ? sm2g : sm1g) + (size_t)bl*SS*KP;
            float* ng       = (which ? n2g : n1g) + bl*SS;
            const float* vg = (which ? v2g : v1g) + bl*SS;
            const float* wv = which ? wc : wr;
            for (int rr = 0; rr < 16; rr++){
                int r = w*16 + rr;
                float wm = (r > 0)   ? wv[r-1] : 0.f;
                float w0 = wv[r];
                float wp = (r < 127) ? wv[r+1] : 0.f;
                float vr = vg[r];
                float nacc = 0.f;
                for (int e = lane; e < KP; e += 64){
                    if (e < EE){
                        float po = og[r*EE + e] * w0;
                        if (r > 0)   po += og[(r-1)*EE + e] * wm;
                        if (r < 127) po += og[(r+1)*EE + e] * wp;
                        float ns = sg[r*EE + e] + po * (1.f/3.f);
                        sg[r*EE + e] = ns;
                        float sv = ns * vr;
                        smg[r*KP + e] = (_Float16)sv;
                        nacc += sv*sv;
                    } else {
                        smg[r*KP + e] = (_Float16)0.f;
                    }
                }
                #pragma unroll
                for (int o = 32; o > 0; o >>= 1) nacc += __shfl_down(nacc, o);
                if (lane == 0) ng[r] = nacc;
            }
        }
    }
}

// ---------------- f = Asrc(128x128 fp16) @ W via Wt[e][j] fp16 -> fp32 f ----
// grid (bc, 4 e-slices); block 256 (4 waves); wave = 32 i x 80 e
__global__ __launch_bounds__(256, 4) void f_mfma(
    const _Float16* __restrict__ Asrc, const _Float16* __restrict__ Wt,
    float* __restrict__ fdst)
{
    __shared__ _Float16 At[128][136];
    int bl = blockIdx.x, es = blockIdx.y;
    int e0 = es*80;
    int tid = threadIdx.x, w = tid >> 6, lane = tid & 63;
    int m = lane & 15, quad = lane >> 4;
    const _Float16* gA = Asrc + (size_t)bl*SS*SS;
    #pragma unroll
    for (int u = 0; u < 8; u++){
        int idx = tid + u*256;
        int row = idx >> 4, jc = (idx & 15)*8;
        *(float4*)&At[row][jc] = *(const float4*)(gA + row*SS + jc);
    }
    __syncthreads();
    f32x4 acc[2][5];
    #pragma unroll
    for (int f = 0; f < 2; f++)
        #pragma unroll
        for (int c = 0; c < 5; c++) acc[f][c] = (f32x4){0.f,0.f,0.f,0.f};
    #pragma unroll
    for (int kc = 0; kc < 4; kc++){
        half8 a0 = *(const half8*)&At[w*32 + m][kc*32 + quad*8];
        half8 a1 = *(const half8*)&At[w*32 + 16 + m][kc*32 + quad*8];
        #pragma unroll
        for (int c = 0; c < 5; c++){
            int e = e0 + c*16 + m;
            half8 b = *(const half8*)(Wt + (size_t)e*SS + kc*32 + quad*8);
            acc[0][c] = __builtin_amdgcn_mfma_f32_16x16x32_f16(a0, b, acc[0][c], 0, 0, 0);
            acc[1][c] = __builtin_amdgcn_mfma_f32_16x16x32_f16(a1, b, acc[1][c], 0, 0, 0);
        }
    }
    float* fo = fdst + (size_t)bl*SS*EE;
    #pragma unroll
    for (int f = 0; f < 2; f++)
        #pragma unroll
        for (int c = 0; c < 5; c++){
            int e = e0 + c*16 + m;
            if (e < EE){
                #pragma unroll
                for (int r = 0; r < 4; r++){
                    int i = w*32 + f*16 + quad*4 + r;
                    fo[(size_t)i*EE + e] = acc[f][c][r];
                }
            }
        }
}

// ---------------- conv(3x3,2ch) + tanh + mean(o) + masked fp16 om + norms ----
// grid: (bc, 2), block 256
__global__ __launch_bounds__(256) void conv_fused_kernel(
    const float* __restrict__ s1, const float* __restrict__ s2,
    const float* __restrict__ f1, const float* __restrict__ f2,
    const float* __restrict__ cw, const float* __restrict__ cb,
    float* __restrict__ o1, float* __restrict__ o2,
    _Float16* __restrict__ om1, _Float16* __restrict__ om2,
    float* __restrict__ no1, float* __restrict__ no2,
    const float* __restrict__ v1, const float* __restrict__ v2,
    float* __restrict__ res, int b0, int seg){
    int bl = blockIdx.x, which = blockIdx.y;
    const float* ca = (which ? s2 : s1) + (size_t)bl*SS*EE;
    const float* cf = (which ? f2 : f1) + (size_t)bl*SS*EE;
    float* od = (which ? o2 : o1) + (size_t)bl*SS*EE;
    _Float16* omr = (which ? om2 : om1) + (size_t)bl*SS*KP;
    float* nog = (which ? no2 : no1) + bl*SS;
    const float* vg = (which ? v2 : v1) + bl*SS;
    float w[2][3][3];
    #pragma unroll
    for (int c = 0; c < 2; c++)
        #pragma unroll
        for (int dy = 0; dy < 3; dy++)
            #pragma unroll
            for (int dx = 0; dx < 3; dx++)
                w[c][dy][dx] = cw[c*9 + dy*3 + dx];
    float bias = cb[0];

    int tid = threadIdx.x;
    int ec = tid & 31, rg = tid >> 5;      // 32 e-chunks x 8 row-groups
    int e0 = ec * 10;
    float msum[10];
    #pragma unroll
    for (int j = 0; j < 10; j++) msum[j] = 0.f;

    for (int pass = 0; pass < 16; pass++){
        int r = rg + pass*8;
        float vr = vg[r];
        float acc[10];
        #pragma unroll
        for (int j = 0; j < 10; j++) acc[j] = bias;
        #pragma unroll
        for (int c = 0; c < 2; c++){
            const float* src = c ? cf : ca;
            #pragma unroll
            for (int dy = 0; dy < 3; dy++){
                int gr = r + dy - 1;
                if (gr < 0 || gr >= SS) continue;
                const float* row = src + (size_t)gr*EE;
                float x[12];
                #pragma unroll
                for (int t = 0; t < 12; t++){
                    int ge = e0 + t - 1;
                    x[t] = (ge >= 0 && ge < EE) ? row[ge] : 0.f;
                }
                #pragma unroll
                for (int j = 0; j < 10; j++)
                    acc[j] = fmaf(w[c][dy][0], x[j],
                              fmaf(w[c][dy][1], x[j+1],
                               fmaf(w[c][dy][2], x[j+2], acc[j])));
            }
        }
        float nacc = 0.f;
        #pragma unroll
        for (int j = 0; j < 10; j++){
            int e = e0 + j;
            if (e < EE){
                float t = fast_tanh(acc[j]);
                od[(size_t)r*EE + e] = t;
                msum[j] += t;
                omr[r*KP + e] = (_Float16)(t * vr);
                nacc += t*t;
            } else {
                omr[r*KP + e] = (_Float16)0.f;
            }
        }
        // reduce norm over the 32 ec-lanes (half-wave)
        #pragma unroll
        for (int mask = 1; mask < 32; mask <<= 1) nacc += __shfl_xor(nacc, mask);
        if (ec == 0) nog[r] = nacc * vr;
    }
    __shared__ float red[8][320];
    #pragma unroll
    for (int j = 0; j < 10; j++) red[rg][e0+j] = msum[j];
    __syncthreads();
    float* rr = res + (size_t)(b0+bl)*FCIN + which*900 + seg*300;
    for (int e = tid; e < EE; e += 256){
        float s = 0.f;
        #pragma unroll
        for (int g = 0; g < 8; g++) s += red[g][e];
        rr[e] = s * (1.f/SS);
    }
}

// ---------------- fc1: [512,1800] @ [1800,300]^T ----------------
#define CKK 12
__global__ __launch_bounds__(256) void fc1_kernel(const float* __restrict__ res,
                                                  const float* __restrict__ fw,
                                                  const float* __restrict__ fb,
                                                  float* __restrict__ h){
    __shared__ float Xt[CKK][68];
    __shared__ float Wt[CKK][68];
    int bt = blockIdx.x, jt = blockIdx.y;
    int tid = threadIdx.x, tx = tid & 15, ty = tid >> 4;
    int b0l = bt*64, j0 = jt*64;
    float acc[4][4] = {};
    for (int k0 = 0; k0 < FCIN; k0 += CKK){
        #pragma unroll
        for (int u = 0; u < 3; u++){
            int idx = tid + u*256;
            int a = idx / CKK, k = idx - a*CKK;
            Xt[k][a] = res[(size_t)(b0l+a)*FCIN + k0 + k];
            int gj = j0 + a;
            Wt[k][a] = (gj < HH) ? fw[(size_t)gj*FCIN + k0 + k] : 0.f;
        }
        __syncthreads();
        #pragma unroll
        for (int k = 0; k < CKK; k++){
            float xv[4], wv[4];
            #pragma unroll
            for (int r = 0; r < 4; r++) xv[r] = Xt[k][ty*4+r];
            #pragma unroll
            for (int c = 0; c < 4; c++) wv[c] = Wt[k][tx*4+c];
            #pragma unroll
            for (int r = 0; r < 4; r++)
                #pragma unroll
                for (int c = 0; c < 4; c++)
                    acc[r][c] = fmaf(xv[r], wv[c], acc[r][c]);
        }
        __syncthreads();
    }
    #pragma unroll
    for (int r = 0; r < 4; r++){
        int gb = b0l + ty*4 + r;
        #pragma unroll
        for (int c = 0; c < 4; c++){
            int gj = j0 + tx*4 + c;
            if (gj < HH) h[(size_t)gb*HH + gj] = acc[r][c] + fb[gj];
        }
    }
}

// ---------------- layernorm + relu + fc2 + softmax ----------------
__global__ void head_kernel(const float* __restrict__ h, const float* __restrict__ g,
                            const float* __restrict__ be, const float* __restrict__ f2w,
                            const float* __restrict__ f2b, float* __restrict__ out){
    int b = blockIdx.x, tid = threadIdx.x;
    __shared__ float arr[HH];
    __shared__ float s_s[4], s_q[4], r0[4], r1[4];
    float x0 = (tid < HH) ? h[(size_t)b*HH + tid] : 0.f;
    float x1 = (tid + 256 < HH) ? h[(size_t)b*HH + tid + 256] : 0.f;
    float s = x0 + x1, sq = x0*x0 + x1*x1;
    #pragma unroll
    for (int o = 32; o > 0; o >>= 1){ s += __shfl_down(s, o); sq += __shfl_down(sq, o); }
    int wv = tid >> 6, ln = tid & 63;
    if (ln == 0){ s_s[wv] = s; s_q[wv] = sq; }
    __syncthreads();
    s  = s_s[0] + s_s[1] + s_s[2] + s_s[3];
    sq = s_q[0] + s_q[1] + s_q[2] + s_q[3];
    float mean = s / HH;
    float var = sq / HH - mean*mean;
    float inv = rsqrtf(var + 1e-5f);
    if (tid < HH)       arr[tid]     = fmaxf((x0 - mean)*inv*g[tid]     + be[tid],     0.f);
    if (tid + 256 < HH) arr[tid+256] = fmaxf((x1 - mean)*inv*g[tid+256] + be[tid+256], 0.f);
    __syncthreads();
    float p0 = 0.f, p1 = 0.f;
    for (int j = tid; j < HH; j += 256){ float hv = arr[j]; p0 += hv*f2w[j]; p1 += hv*f2w[HH+j]; }
    #pragma unroll
    for (int o = 32; o > 0; o >>= 1){ p0 += __shfl_down(p0, o); p1 += __shfl_down(p1, o); }
    if (ln == 0){ r0[wv] = p0; r1[wv] = p1; }
    __syncthreads();
    if (tid == 0){
        float o0 = r0[0]+r0[1]+r0[2]+r0[3] + f2b[0];
        float o1 = r1[0]+r1[1]+r1[2]+r1[3] + f2b[1];
        out[b*2+0] = o0; out[b*2+1] = o1;
        float m = fmaxf(o0, o1);
        float e0 = __expf(o0 - m), e1 = __expf(o1 - m);
        float den = e0 + e1;
        out[BB*2 + b*2+0] = e0/den;
        out[BB*2 + b*2+1] = e1/den;
    }
}

extern "C" void kernel_launch(void* const* d_in, const int* in_sizes, int n_in,
                              void* d_out, int out_size, void* d_ws, size_t ws_size,
                              hipStream_t stream){
    const int*   seq1   = (const int*)d_in[0];
    const int*   seq2   = (const int*)d_in[1];
    const float* emb    = (const float*)d_in[2];
    const float* W      = (const float*)d_in[3];
    const float* conv_w = (const float*)d_in[4];
    const float* conv_b = (const float*)d_in[5];
    const float* fc1_w  = (const float*)d_in[6];
    const float* fc1_b  = (const float*)d_in[7];
    const float* ln_g   = (const float*)d_in[8];
    const float* ln_b   = (const float*)d_in[9];
    const float* fc2_w  = (const float*)d_in[10];
    const float* fc2_b  = (const float*)d_in[11];
    float* out = (float*)d_out;

    float* ws = (float*)d_ws;
    // fixed region (floats): res + hb + Wt(fp16 as 40960 floats)
    size_t fixedf = (size_t)BB*FCIN + (size_t)BB*HH + 2*KP*SS/2;
    // per-batch floats: 6 fp32 tensors + 4 fp16 KP-tensors + A/At fp16 + 6 vec
    size_t perb = (size_t)6*SS*EE + 4*(SS*KP/2) + 2*(SS*SS/2) + 6*SS;
    size_t avail = ws_size / 4;
    long long bcl = (long long)((avail > fixedf ? avail - fixedf : 0) / perb);
    int BC = (int)(bcl < 1 ? 1 : (bcl > BB ? BB : bcl));

    float* res = ws;
    float* hb  = res + (size_t)BB*FCIN;
    _Float16* Wt = (_Float16*)(hb + (size_t)BB*HH);
    float* base = hb + (size_t)BB*HH + 2*KP*SS/2;
    float* s1  = base;
    float* s2  = s1  + (size_t)BC*SS*EE;
    float* f1b = s2  + (size_t)BC*SS*EE;
    float* f2b = f1b + (size_t)BC*SS*EE;
    float* o1  = f2b + (size_t)BC*SS*EE;
    float* o2  = o1  + (size_t)BC*SS*EE;
    _Float16* sm1 = (_Float16*)(o2 + (size_t)BC*SS*EE);
    _Float16* sm2 = sm1 + (size_t)BC*SS*KP;
    _Float16* om1 = sm2 + (size_t)BC*SS*KP;
    _Float16* om2 = om1 + (size_t)BC*SS*KP;
    _Float16* Ab  = om2 + (size_t)BC*SS*KP;
    _Float16* At  = Ab  + (size_t)BC*SS*SS;
    float* n1  = (float*)(At + (size_t)BC*SS*SS);
    float* n2  = n1 + (size_t)BC*SS;
    float* no1 = n2 + (size_t)BC*SS;
    float* no2 = no1 + (size_t)BC*SS;
    float* v1  = no2 + (size_t)BC*SS;
    float* v2  = v1 + (size_t)BC*SS;

    wt_build_kernel<<<(2*KP*SS + 255)/256, 256, 0, stream>>>(W, Wt);

    for (int b0 = 0; b0 < BB; b0 += BC){
        int bc = (BB - b0 < BC) ? (BB - b0) : BC;
        embed_mean_kernel<<<dim3(bc, 2), 256, 0, stream>>>(seq1, seq2, emb, s1, s2, v1, v2,
                                                           sm1, sm2, n1, n2, res, b0);
        for (int it = 0; it < LLI; it++){
            cross_mfma<0><<<bc, 512, 0, stream>>>(sm1, sm2, n1, n2, Ab, At,
                                                  nullptr, nullptr, nullptr, nullptr,
                                                  nullptr, nullptr, nullptr, nullptr,
                                                  nullptr, nullptr);
            f_mfma<<<dim3(bc, 4), 256, 0, stream>>>(Ab, Wt + (size_t)it*KP*SS, f1b);
            f_mfma<<<dim3(bc, 4), 256, 0, stream>>>(At, Wt + (size_t)it*KP*SS, f2b);
            conv_fused_kernel<<<dim3(bc, 2), 256, 0, stream>>>(s1, s2, f1b, f2b,
                                                               conv_w + it*18, conv_b + it,
                                                               o1, o2, om1, om2, no1, no2,
                                                               v1, v2, res, b0, it+1);
            cross_mfma<1><<<bc, 512, 0, stream>>>(om1, om2, no1, no2, nullptr, nullptr,
                                                  o1, o2, s1, s2, sm1, sm2, n1, n2, v1, v2);
        }
    }
    fc1_kernel<<<dim3(8, 5), 256, 0, stream>>>(res, fc1_w, fc1_b, hb);
    head_kernel<<<BB, 256, 0, stream>>>(hb, ln_g, ln_b, fc2_w, fc2_b, out);
}

// Round 5
// 1867.684 us; speedup vs baseline: 2.1811x; 1.5961x over previous
//
#include <hip/hip_runtime.h>
#include <math.h>

#define BB 512
#define SS 128
#define EE 300
#define HH 300
#define FCIN 1800
#define LLI 2
#define KP 320          // padded K for fp16 GEMM operands

using half8 = __attribute__((ext_vector_type(8))) _Float16;
using f32x4 = __attribute__((ext_vector_type(4))) float;

__device__ __forceinline__ float fast_tanh(float x){
    float ax = fabsf(x);
    float t = __expf(-2.f*ax);
    float r = (1.f - t) / (1.f + t);
    return copysignf(r, x);
}

// ---------------- Wt build: Wt[it][e][j] = W[it][j][e], fp16, e zero-padded to 320
__global__ void wt_build_kernel(const float* __restrict__ W, _Float16* __restrict__ Wt){
    int idx = blockIdx.x*256 + threadIdx.x;      // 2*320*128 = 81920
    if (idx >= 2*KP*SS) return;
    int j = idx & 127;
    int e = (idx >> 7) % KP;
    int it = idx / (KP*SS);
    float v = (e < EE) ? W[(size_t)it*SS*EE + j*EE + e] : 0.f;
    Wt[idx] = (_Float16)v;
}

// ---------------- embedding gather + v + mean(s) + masked fp16 sm + norms ----
// grid: (bc, 2), block 256
__global__ void embed_mean_kernel(const int* __restrict__ seq1, const int* __restrict__ seq2,
                                  const float* __restrict__ emb,
                                  float* __restrict__ s1, float* __restrict__ s2,
                                  float* __restrict__ v1, float* __restrict__ v2,
                                  _Float16* __restrict__ sm1, _Float16* __restrict__ sm2,
                                  float* __restrict__ n1, float* __restrict__ n2,
                                  float* __restrict__ res, int b0){
    int bl = blockIdx.x, which = blockIdx.y;
    const int* seq = which ? seq2 : seq1;
    float* sd = which ? s2 : s1;
    float* vd = which ? v2 : v1;
    int tid = threadIdx.x;
    int e1 = tid, e2 = tid + 256;
    float acc1 = 0.f, acc2 = 0.f;
    for (int s = 0; s < SS; s++){
        int token = seq[(size_t)(b0+bl)*SS + s];
        if (tid == 0) vd[bl*SS + s] = (token != 0) ? 1.f : 0.f;
        const float* er = emb + (size_t)token * EE;
        float* orow = sd + ((size_t)bl*SS + s) * EE;
        if (e1 < EE){ float v = er[e1]; orow[e1] = v; acc1 += v; }
        if (e2 < EE){ float v = er[e2]; orow[e2] = v; acc2 += v; }
    }
    float* rr = res + (size_t)(b0+bl)*FCIN + which*900;
    if (e1 < EE) rr[e1] = acc1 * (1.f/SS);
    if (e2 < EE) rr[e2] = acc2 * (1.f/SS);
    __syncthreads();
    // phase 2: masked fp16 copy + row norms
    _Float16* smg = (which ? sm2 : sm1) + (size_t)bl*SS*KP;
    float* ng = (which ? n2 : n1) + bl*SS;
    int wv = tid >> 6, lane = tid & 63;
    for (int row = wv; row < SS; row += 4){
        int token = seq[(size_t)(b0+bl)*SS + row];
        float vr = (token != 0) ? 1.f : 0.f;
        const float* sr = sd + ((size_t)bl*SS + row) * EE;
        float acc = 0.f;
        for (int e = lane; e < KP; e += 64){
            if (e < EE){
                float sv = sr[e] * vr;
                smg[row*KP + e] = (_Float16)sv;
                acc += sv*sv;
            } else {
                smg[row*KP + e] = (_Float16)0.f;
            }
        }
        #pragma unroll
        for (int o = 32; o > 0; o >>= 1) acc += __shfl_down(acc, o);
        if (lane == 0) ng[row] = acc;
    }
}

// ---------------- MFMA match (A-producing): 128x128, K=320 fp16 ----------------
// block 512 (8 waves); wave = 16 rows x 128 cols (8 c-frags)
__global__ __launch_bounds__(512, 4) void cross_matchA(
    const _Float16* __restrict__ smA, const _Float16* __restrict__ smB,
    const float* __restrict__ nAg, const float* __restrict__ nBg,
    _Float16* __restrict__ Ab16, _Float16* __restrict__ At16)
{
    __shared__ _Float16 As[128][40];
    __shared__ _Float16 Bs[128][40];
    __shared__ float nAl[128], nBl[128];

    int bl = blockIdx.x;
    int tid = threadIdx.x;
    int w = tid >> 6, lane = tid & 63;
    int m = lane & 15, quad = lane >> 4;

    const _Float16* gA = smA + (size_t)bl*SS*KP;
    const _Float16* gB = smB + (size_t)bl*SS*KP;

    if (tid < 128) nAl[tid] = nAg[bl*SS + tid];
    else if (tid < 256) nBl[tid-128] = nBg[bl*SS + tid-128];

    f32x4 acc[8];
    #pragma unroll
    for (int c = 0; c < 8; c++) acc[c] = (f32x4){0.f,0.f,0.f,0.f};

    int srow = tid >> 2, skq = (tid & 3) * 8;
    int arow = w*16 + m;

    for (int kc = 0; kc < 10; kc++){
        __syncthreads();
        *(float4*)&As[srow][skq] = *(const float4*)(gA + srow*KP + kc*32 + skq);
        *(float4*)&Bs[srow][skq] = *(const float4*)(gB + srow*KP + kc*32 + skq);
        __syncthreads();
        half8 a = *(const half8*)&As[arow][quad*8];
        #pragma unroll
        for (int c = 0; c < 8; c++){
            half8 b = *(const half8*)&Bs[c*16 + m][quad*8];
            acc[c] = __builtin_amdgcn_mfma_f32_16x16x32_f16(a, b, acc[c], 0, 0, 0);
        }
    }

    int ibase = w*16 + quad*4;
    _Float16* Ao  = Ab16 + (size_t)bl*SS*SS;
    _Float16* Ato = At16 + (size_t)bl*SS*SS;
    #pragma unroll
    for (int c = 0; c < 8; c++){
        int j = c*16 + m;
        float nc = nBl[j];
        #pragma unroll
        for (int r = 0; r < 4; r++){
            int i = ibase + r;
            float d2 = nAl[i] + nc - 2.f*acc[c][r];
            float d = sqrtf(fmaxf(d2, 0.f));
            _Float16 hv = (_Float16)(1.f / (1.f + d));
            Ao[i*SS + j]  = hv;
            Ato[j*SS + i] = hv;
        }
    }
}

// ---------------- MFMA match (sums only): stages o16*v, outputs w1/w2 ---------
__global__ __launch_bounds__(512, 4) void cross_sums(
    const _Float16* __restrict__ oA, const _Float16* __restrict__ oB,
    const float* __restrict__ noA, const float* __restrict__ noB,
    const float* __restrict__ vAg, const float* __restrict__ vBg,
    float* __restrict__ w1g, float* __restrict__ w2g)
{
    __shared__ _Float16 As[128][40];
    __shared__ _Float16 Bs[128][40];
    __shared__ float nAl[128], nBl[128], vAl[128], vBl[128];
    __shared__ float colred[8][132];

    int bl = blockIdx.x;
    int tid = threadIdx.x;
    int w = tid >> 6, lane = tid & 63;
    int m = lane & 15, quad = lane >> 4;

    const _Float16* gA = oA + (size_t)bl*SS*KP;
    const _Float16* gB = oB + (size_t)bl*SS*KP;

    if (tid < 128){ nAl[tid] = noA[bl*SS + tid]; vAl[tid] = vAg[bl*SS + tid]; }
    else if (tid < 256){ nBl[tid-128] = noB[bl*SS + tid-128]; vBl[tid-128] = vBg[bl*SS + tid-128]; }

    f32x4 acc[8];
    #pragma unroll
    for (int c = 0; c < 8; c++) acc[c] = (f32x4){0.f,0.f,0.f,0.f};

    int srow = tid >> 2, skq = (tid & 3) * 8;
    int arow = w*16 + m;

    for (int kc = 0; kc < 10; kc++){
        __syncthreads();
        {
            half8 ha = *(const half8*)(gA + srow*KP + kc*32 + skq);
            half8 hb = *(const half8*)(gB + srow*KP + kc*32 + skq);
            _Float16 va = (_Float16)vAl[srow];
            _Float16 vb = (_Float16)vBl[srow];
            ha = ha * va;
            hb = hb * vb;
            *(half8*)&As[srow][skq] = ha;
            *(half8*)&Bs[srow][skq] = hb;
        }
        __syncthreads();
        half8 a = *(const half8*)&As[arow][quad*8];
        #pragma unroll
        for (int c = 0; c < 8; c++){
            half8 b = *(const half8*)&Bs[c*16 + m][quad*8];
            acc[c] = __builtin_amdgcn_mfma_f32_16x16x32_f16(a, b, acc[c], 0, 0, 0);
        }
    }

    int ibase = w*16 + quad*4;
    float aval[8][4];
    #pragma unroll
    for (int c = 0; c < 8; c++){
        float nc = nBl[c*16 + m];
        #pragma unroll
        for (int r = 0; r < 4; r++){
            float d2 = nAl[ibase+r] + nc - 2.f*acc[c][r];
            float d = sqrtf(fmaxf(d2, 0.f));
            aval[c][r] = 1.f / (1.f + d);
        }
    }

    // row sums -> w1
    float rp[4];
    #pragma unroll
    for (int r = 0; r < 4; r++){
        float s = 0.f;
        #pragma unroll
        for (int c = 0; c < 8; c++) s += aval[c][r];
        rp[r] = s;
    }
    #pragma unroll
    for (int mask = 1; mask < 16; mask <<= 1)
        #pragma unroll
        for (int r = 0; r < 4; r++) rp[r] += __shfl_xor(rp[r], mask);
    if (m == 0){
        #pragma unroll
        for (int r = 0; r < 4; r++) w1g[bl*SS + ibase + r] = rp[r];
    }
    // col sums -> w2
    float cp[8];
    #pragma unroll
    for (int c = 0; c < 8; c++){
        float s = 0.f;
        #pragma unroll
        for (int r = 0; r < 4; r++) s += aval[c][r];
        cp[c] = s;
    }
    #pragma unroll
    for (int c = 0; c < 8; c++){
        cp[c] += __shfl_xor(cp[c], 16);
        cp[c] += __shfl_xor(cp[c], 32);
    }
    if (quad == 0){
        #pragma unroll
        for (int c = 0; c < 8; c++) colred[w][c*16 + m] = cp[c];
    }
    __syncthreads();
    if (tid < 128){
        float s = 0.f;
        #pragma unroll
        for (int g = 0; g < 8; g++) s += colred[g][tid];
        w2g[bl*SS + tid] = s;
    }
}

// ---------------- pool: s += avg3(o*w); write sm (masked fp16) + norms -------
// grid (bc, 8, 2), block 256 (4 waves; wave = 4 rows)
__global__ __launch_bounds__(256) void pool_kernel(
    const _Float16* __restrict__ o16_1, const _Float16* __restrict__ o16_2,
    const float* __restrict__ w1g, const float* __restrict__ w2g,
    const float* __restrict__ v1g, const float* __restrict__ v2g,
    float* __restrict__ s1g, float* __restrict__ s2g,
    _Float16* __restrict__ sm1, _Float16* __restrict__ sm2,
    float* __restrict__ n1, float* __restrict__ n2)
{
    int bl = blockIdx.x, chunk = blockIdx.y, which = blockIdx.z;
    const _Float16* og = (which ? o16_2 : o16_1) + (size_t)bl*SS*KP;
    const float* wg = (which ? w2g : w1g) + bl*SS;
    const float* vg = (which ? v2g : v1g) + bl*SS;
    float* sg = (which ? s2g : s1g) + (size_t)bl*SS*EE;
    _Float16* smg = (which ? sm2 : sm1) + (size_t)bl*SS*KP;
    float* ng = (which ? n2 : n1) + bl*SS;
    int wv = threadIdx.x >> 6, lane = threadIdx.x & 63;
    #pragma unroll
    for (int rr = 0; rr < 4; rr++){
        int r = chunk*16 + wv*4 + rr;
        float w0 = wg[r];
        float wm = (r > 0)   ? wg[r-1] : 0.f;
        float wp = (r < 127) ? wg[r+1] : 0.f;
        float vr = vg[r];
        float nacc = 0.f;
        #pragma unroll
        for (int k = 0; k < 5; k++){
            int e = lane + k*64;               // < 320
            float a = (float)og[r*KP + e] * w0;
            if (r > 0)   a += (float)og[(r-1)*KP + e] * wm;
            if (r < 127) a += (float)og[(r+1)*KP + e] * wp;
            if (e < EE){
                float ns = sg[r*EE + e] + a * (1.f/3.f);
                sg[r*EE + e] = ns;
                float sv = ns * vr;
                smg[r*KP + e] = (_Float16)sv;
                nacc += sv*sv;
            } else {
                smg[r*KP + e] = (_Float16)0.f;
            }
        }
        #pragma unroll
        for (int o = 32; o > 0; o >>= 1) nacc += __shfl_down(nacc, o);
        if (lane == 0) ng[r] = nacc;
    }
}

// ---------------- f = Asrc(128x128 fp16) @ W via Wt[e][j] fp16 -> fp16 f -----
// grid (bc, 4, 2); block 256 (4 waves); wave = 32 i x 80 e; z: 0=Ab->f1, 1=At->f2
__global__ __launch_bounds__(256, 4) void f_mfma(
    const _Float16* __restrict__ Ab, const _Float16* __restrict__ At,
    const _Float16* __restrict__ Wt,
    _Float16* __restrict__ f1, _Float16* __restrict__ f2)
{
    __shared__ _Float16 Atile[128][136];
    int bl = blockIdx.x, es = blockIdx.y, zz = blockIdx.z;
    int e0 = es*80;
    int tid = threadIdx.x, w = tid >> 6, lane = tid & 63;
    int m = lane & 15, quad = lane >> 4;
    const _Float16* gA = (zz ? At : Ab) + (size_t)bl*SS*SS;
    #pragma unroll
    for (int u = 0; u < 8; u++){
        int idx = tid + u*256;
        int row = idx >> 4, jc = (idx & 15)*8;
        *(float4*)&Atile[row][jc] = *(const float4*)(gA + row*SS + jc);
    }
    __syncthreads();
    f32x4 acc[2][5];
    #pragma unroll
    for (int f = 0; f < 2; f++)
        #pragma unroll
        for (int c = 0; c < 5; c++) acc[f][c] = (f32x4){0.f,0.f,0.f,0.f};
    #pragma unroll
    for (int kc = 0; kc < 4; kc++){
        half8 a0 = *(const half8*)&Atile[w*32 + m][kc*32 + quad*8];
        half8 a1 = *(const half8*)&Atile[w*32 + 16 + m][kc*32 + quad*8];
        #pragma unroll
        for (int c = 0; c < 5; c++){
            int e = e0 + c*16 + m;
            half8 b = *(const half8*)(Wt + (size_t)e*SS + kc*32 + quad*8);
            acc[0][c] = __builtin_amdgcn_mfma_f32_16x16x32_f16(a0, b, acc[0][c], 0, 0, 0);
            acc[1][c] = __builtin_amdgcn_mfma_f32_16x16x32_f16(a1, b, acc[1][c], 0, 0, 0);
        }
    }
    _Float16* fo = (zz ? f2 : f1) + (size_t)bl*SS*EE;
    #pragma unroll
    for (int f = 0; f < 2; f++)
        #pragma unroll
        for (int c = 0; c < 5; c++){
            int e = e0 + c*16 + m;
            if (e < EE){
                #pragma unroll
                for (int r = 0; r < 4; r++){
                    int i = w*32 + f*16 + quad*4 + r;
                    fo[(size_t)i*EE + e] = (_Float16)acc[f][c][r];
                }
            }
        }
}

// ---------------- conv(3x3,2ch fp32 s + fp16 f) + tanh + mean + o16 + norms --
// grid: (bc, 2), block 256
__global__ __launch_bounds__(256) void conv_fused_kernel(
    const float* __restrict__ s1, const float* __restrict__ s2,
    const _Float16* __restrict__ f1, const _Float16* __restrict__ f2,
    const float* __restrict__ cw, const float* __restrict__ cb,
    _Float16* __restrict__ o16_1, _Float16* __restrict__ o16_2,
    float* __restrict__ no1, float* __restrict__ no2,
    const float* __restrict__ v1, const float* __restrict__ v2,
    float* __restrict__ res, int b0, int seg){
    int bl = blockIdx.x, which = blockIdx.y;
    const float* ca = (which ? s2 : s1) + (size_t)bl*SS*EE;
    const _Float16* cf = (which ? f2 : f1) + (size_t)bl*SS*EE;
    _Float16* od = (which ? o16_2 : o16_1) + (size_t)bl*SS*KP;
    float* nog = (which ? no2 : no1) + bl*SS;
    const float* vg = (which ? v2 : v1) + bl*SS;
    float w[2][3][3];
    #pragma unroll
    for (int c = 0; c < 2; c++)
        #pragma unroll
        for (int dy = 0; dy < 3; dy++)
            #pragma unroll
            for (int dx = 0; dx < 3; dx++)
                w[c][dy][dx] = cw[c*9 + dy*3 + dx];
    float bias = cb[0];

    int tid = threadIdx.x;
    int ec = tid & 31, rg = tid >> 5;      // 32 e-chunks x 8 row-groups
    int e0 = ec * 10;
    float msum[10];
    #pragma unroll
    for (int j = 0; j < 10; j++) msum[j] = 0.f;

    for (int pass = 0; pass < 16; pass++){
        int r = rg + pass*8;
        float vr = vg[r];
        float acc[10];
        #pragma unroll
        for (int j = 0; j < 10; j++) acc[j] = bias;
        // channel 0: fp32 s
        #pragma unroll
        for (int dy = 0; dy < 3; dy++){
            int gr = r + dy - 1;
            if (gr < 0 || gr >= SS) continue;
            const float* row = ca + (size_t)gr*EE;
            float x[12];
            #pragma unroll
            for (int t = 0; t < 12; t++){
                int ge = e0 + t - 1;
                x[t] = (ge >= 0 && ge < EE) ? row[ge] : 0.f;
            }
            #pragma unroll
            for (int j = 0; j < 10; j++)
                acc[j] = fmaf(w[0][dy][0], x[j],
                          fmaf(w[0][dy][1], x[j+1],
                           fmaf(w[0][dy][2], x[j+2], acc[j])));
        }
        // channel 1: fp16 f
        #pragma unroll
        for (int dy = 0; dy < 3; dy++){
            int gr = r + dy - 1;
            if (gr < 0 || gr >= SS) continue;
            const _Float16* row = cf + (size_t)gr*EE;
            float x[12];
            #pragma unroll
            for (int t = 0; t < 12; t++){
                int ge = e0 + t - 1;
                x[t] = (ge >= 0 && ge < EE) ? (float)row[ge] : 0.f;
            }
            #pragma unroll
            for (int j = 0; j < 10; j++)
                acc[j] = fmaf(w[1][dy][0], x[j],
                          fmaf(w[1][dy][1], x[j+1],
                           fmaf(w[1][dy][2], x[j+2], acc[j])));
        }
        float nacc = 0.f;
        #pragma unroll
        for (int j = 0; j < 10; j++){
            int e = e0 + j;
            if (e < EE){
                float t = fast_tanh(acc[j]);
                od[r*KP + e] = (_Float16)t;
                msum[j] += t;
                nacc += t*t;
            } else {
                od[r*KP + e] = (_Float16)0.f;
            }
        }
        #pragma unroll
        for (int mask = 1; mask < 32; mask <<= 1) nacc += __shfl_xor(nacc, mask);
        if (ec == 0) nog[r] = nacc * vr;
    }
    __shared__ float red[8][320];
    #pragma unroll
    for (int j = 0; j < 10; j++) red[rg][e0+j] = msum[j];
    __syncthreads();
    float* rr = res + (size_t)(b0+bl)*FCIN + which*900 + seg*300;
    for (int e = tid; e < EE; e += 256){
        float s = 0.f;
        #pragma unroll
        for (int g = 0; g < 8; g++) s += red[g][e];
        rr[e] = s * (1.f/SS);
    }
}

// ---------------- fc1: [512,1800] @ [1800,300]^T ----------------
#define CKK 12
__global__ __launch_bounds__(256) void fc1_kernel(const float* __restrict__ res,
                                                  const float* __restrict__ fw,
                                                  const float* __restrict__ fb,
                                                  float* __restrict__ h){
    __shared__ float Xt[CKK][68];
    __shared__ float Wt[CKK][68];
    int bt = blockIdx.x, jt = blockIdx.y;
    int tid = threadIdx.x, tx = tid & 15, ty = tid >> 4;
    int b0l = bt*64, j0 = jt*64;
    float acc[4][4] = {};
    for (int k0 = 0; k0 < FCIN; k0 += CKK){
        #pragma unroll
        for (int u = 0; u < 3; u++){
            int idx = tid + u*256;
            int a = idx / CKK, k = idx - a*CKK;
            Xt[k][a] = res[(size_t)(b0l+a)*FCIN + k0 + k];
            int gj = j0 + a;
            Wt[k][a] = (gj < HH) ? fw[(size_t)gj*FCIN + k0 + k] : 0.f;
        }
        __syncthreads();
        #pragma unroll
        for (int k = 0; k < CKK; k++){
            float xv[4], wv[4];
            #pragma unroll
            for (int r = 0; r < 4; r++) xv[r] = Xt[k][ty*4+r];
            #pragma unroll
            for (int c = 0; c < 4; c++) wv[c] = Wt[k][tx*4+c];
            #pragma unroll
            for (int r = 0; r < 4; r++)
                #pragma unroll
                for (int c = 0; c < 4; c++)
                    acc[r][c] = fmaf(xv[r], wv[c], acc[r][c]);
        }
        __syncthreads();
    }
    #pragma unroll
    for (int r = 0; r < 4; r++){
        int gb = b0l + ty*4 + r;
        #pragma unroll
        for (int c = 0; c < 4; c++){
            int gj = j0 + tx*4 + c;
            if (gj < HH) h[(size_t)gb*HH + gj] = acc[r][c] + fb[gj];
        }
    }
}

// ---------------- layernorm + relu + fc2 + softmax ----------------
__global__ void head_kernel(const float* __restrict__ h, const float* __restrict__ g,
                            const float* __restrict__ be, const float* __restrict__ f2w,
                            const float* __restrict__ f2b, float* __restrict__ out){
    int b = blockIdx.x, tid = threadIdx.x;
    __shared__ float arr[HH];
    __shared__ float s_s[4], s_q[4], r0[4], r1[4];
    float x0 = (tid < HH) ? h[(size_t)b*HH + tid] : 0.f;
    float x1 = (tid + 256 < HH) ? h[(size_t)b*HH + tid + 256] : 0.f;
    float s = x0 + x1, sq = x0*x0 + x1*x1;
    #pragma unroll
    for (int o = 32; o > 0; o >>= 1){ s += __shfl_down(s, o); sq += __shfl_down(sq, o); }
    int wv = tid >> 6, ln = tid & 63;
    if (ln == 0){ s_s[wv] = s; s_q[wv] = sq; }
    __syncthreads();
    s  = s_s[0] + s_s[1] + s_s[2] + s_s[3];
    sq = s_q[0] + s_q[1] + s_q[2] + s_q[3];
    float mean = s / HH;
    float var = sq / HH - mean*mean;
    float inv = rsqrtf(var + 1e-5f);
    if (tid < HH)       arr[tid]     = fmaxf((x0 - mean)*inv*g[tid]     + be[tid],     0.f);
    if (tid + 256 < HH) arr[tid+256] = fmaxf((x1 - mean)*inv*g[tid+256] + be[tid+256], 0.f);
    __syncthreads();
    float p0 = 0.f, p1 = 0.f;
    for (int j = tid; j < HH; j += 256){ float hv = arr[j]; p0 += hv*f2w[j]; p1 += hv*f2w[HH+j]; }
    #pragma unroll
    for (int o = 32; o > 0; o >>= 1){ p0 += __shfl_down(p0, o); p1 += __shfl_down(p1, o); }
    if (ln == 0){ r0[wv] = p0; r1[wv] = p1; }
    __syncthreads();
    if (tid == 0){
        float o0 = r0[0]+r0[1]+r0[2]+r0[3] + f2b[0];
        float o1 = r1[0]+r1[1]+r1[2]+r1[3] + f2b[1];
        out[b*2+0] = o0; out[b*2+1] = o1;
        float m = fmaxf(o0, o1);
        float e0 = __expf(o0 - m), e1 = __expf(o1 - m);
        float den = e0 + e1;
        out[BB*2 + b*2+0] = e0/den;
        out[BB*2 + b*2+1] = e1/den;
    }
}

extern "C" void kernel_launch(void* const* d_in, const int* in_sizes, int n_in,
                              void* d_out, int out_size, void* d_ws, size_t ws_size,
                              hipStream_t stream){
    const int*   seq1   = (const int*)d_in[0];
    const int*   seq2   = (const int*)d_in[1];
    const float* emb    = (const float*)d_in[2];
    const float* W      = (const float*)d_in[3];
    const float* conv_w = (const float*)d_in[4];
    const float* conv_b = (const float*)d_in[5];
    const float* fc1_w  = (const float*)d_in[6];
    const float* fc1_b  = (const float*)d_in[7];
    const float* ln_g   = (const float*)d_in[8];
    const float* ln_b   = (const float*)d_in[9];
    const float* fc2_w  = (const float*)d_in[10];
    const float* fc2_b  = (const float*)d_in[11];
    float* out = (float*)d_out;

    float* ws = (float*)d_ws;
    // fixed floats: res + hb + Wt(2*KP*SS halves)
    size_t fixedf = (size_t)BB*FCIN + (size_t)BB*HH + (size_t)KP*SS;
    // per-batch floats: 2 fp32 s + (4 KP fp16 + 2 EE fp16 + 2 SS*SS fp16)/2 + 8 vecs
    size_t perb = (size_t)2*SS*EE + ((size_t)4*SS*KP + 2*SS*EE + 2*SS*SS)/2 + 8*SS;
    size_t avail = ws_size / 4;
    long long bcl = (long long)((avail > fixedf ? avail - fixedf : 0) / perb);
    int BC = (int)(bcl < 1 ? 1 : (bcl > BB ? BB : bcl));

    float* res = ws;
    float* hb  = res + (size_t)BB*FCIN;
    _Float16* Wt = (_Float16*)(hb + (size_t)BB*HH);
    float* base = (float*)(Wt + (size_t)2*KP*SS);
    float* s1  = base;
    float* s2  = s1 + (size_t)BC*SS*EE;
    _Float16* sm1 = (_Float16*)(s2 + (size_t)BC*SS*EE);
    _Float16* sm2 = sm1 + (size_t)BC*SS*KP;
    _Float16* o16_1 = sm2 + (size_t)BC*SS*KP;
    _Float16* o16_2 = o16_1 + (size_t)BC*SS*KP;
    _Float16* f16_1 = o16_2 + (size_t)BC*SS*KP;
    _Float16* f16_2 = f16_1 + (size_t)BC*SS*EE;
    _Float16* Ab  = f16_2 + (size_t)BC*SS*EE;
    _Float16* At  = Ab  + (size_t)BC*SS*SS;
    float* n1  = (float*)(At + (size_t)BC*SS*SS);
    float* n2  = n1 + (size_t)BC*SS;
    float* no1 = n2 + (size_t)BC*SS;
    float* no2 = no1 + (size_t)BC*SS;
    float* w1  = no2 + (size_t)BC*SS;
    float* w2  = w1 + (size_t)BC*SS;
    float* v1  = w2 + (size_t)BC*SS;
    float* v2  = v1 + (size_t)BC*SS;

    wt_build_kernel<<<(2*KP*SS + 255)/256, 256, 0, stream>>>(W, Wt);

    for (int b0 = 0; b0 < BB; b0 += BC){
        int bc = (BB - b0 < BC) ? (BB - b0) : BC;
        embed_mean_kernel<<<dim3(bc, 2), 256, 0, stream>>>(seq1, seq2, emb, s1, s2, v1, v2,
                                                           sm1, sm2, n1, n2, res, b0);
        for (int it = 0; it < LLI; it++){
            cross_matchA<<<bc, 512, 0, stream>>>(sm1, sm2, n1, n2, Ab, At);
            f_mfma<<<dim3(bc, 4, 2), 256, 0, stream>>>(Ab, At, Wt + (size_t)it*KP*SS, f16_1, f16_2);
            conv_fused_kernel<<<dim3(bc, 2), 256, 0, stream>>>(s1, s2, f16_1, f16_2,
                                                               conv_w + it*18, conv_b + it,
                                                               o16_1, o16_2, no1, no2,
                                                               v1, v2, res, b0, it+1);
            cross_sums<<<bc, 512, 0, stream>>>(o16_1, o16_2, no1, no2, v1, v2, w1, w2);
            pool_kernel<<<dim3(bc, 8, 2), 256, 0, stream>>>(o16_1, o16_2, w1, w2, v1, v2,
                                                            s1, s2, sm1, sm2, n1, n2);
        }
    }
    fc1_kernel<<<dim3(8, 5), 256, 0, stream>>>(res, fc1_w, fc1_b, hb);
    head_kernel<<<BB, 256, 0, stream>>>(hb, ln_g, ln_b, fc2_w, fc2_b, out);
}

// Round 7
// 1093.734 us; speedup vs baseline: 3.7244x; 1.7076x over previous
//
#include <hip/hip_runtime.h>
#include <math.h>

#define BB 512
#define SS 128
#define EE 300
#define HH 300
#define FCIN 1800
#define LLI 2
#define KP 320          // padded K / leading dim for fp16 tensors

using half8 = __attribute__((ext_vector_type(8))) _Float16;
using f32x4 = __attribute__((ext_vector_type(4))) float;

__device__ __forceinline__ float fast_tanh(float x){
    float ax = fabsf(x);
    float t = __expf(-2.f*ax);
    float r = (1.f - t) / (1.f + t);
    return copysignf(r, x);
}

// ---------------- Wt build: Wt[it][e][j] = W[it][j][e], fp16, e zero-padded to 320
__global__ void wt_build_kernel(const float* __restrict__ W, _Float16* __restrict__ Wt){
    int idx = blockIdx.x*256 + threadIdx.x;      // 2*320*128 = 81920
    if (idx >= 2*KP*SS) return;
    int j = idx & 127;
    int e = (idx >> 7) % KP;
    int it = idx / (KP*SS);
    float v = (e < EE) ? W[(size_t)it*SS*EE + j*EE + e] : 0.f;
    Wt[idx] = (_Float16)v;
}

// ---------------- embed: gather -> sf16 (raw, KP-pad) + masked norms + v -----
// grid (bc, 32, 2), block 256 (4 waves, wave = 1 row)
__global__ __launch_bounds__(256) void embed_kernel(
    const int* __restrict__ seq1, const int* __restrict__ seq2,
    const float* __restrict__ emb,
    _Float16* __restrict__ sf1, _Float16* __restrict__ sf2,
    float* __restrict__ v1, float* __restrict__ v2,
    float* __restrict__ n1, float* __restrict__ n2, int b0){
    int bl = blockIdx.x, which = blockIdx.z;
    int r = blockIdx.y*4 + (threadIdx.x >> 6);
    int l = threadIdx.x & 63;
    const int* seq = which ? seq2 : seq1;
    _Float16* sfg = (which ? sf2 : sf1) + (size_t)bl*SS*KP;
    float* vd = (which ? v2 : v1) + bl*SS;
    float* ng = (which ? n2 : n1) + bl*SS;
    int token = seq[(size_t)(b0+bl)*SS + r];
    float vr = (token != 0) ? 1.f : 0.f;
    if (l == 0) vd[r] = vr;
    const float* er = emb + (size_t)token * EE;
    int e0 = l*8;
    float x[8];
    if (l < 37){
        float4 a = *(const float4*)(er + e0);
        float4 b = *(const float4*)(er + e0 + 4);
        x[0]=a.x; x[1]=a.y; x[2]=a.z; x[3]=a.w;
        x[4]=b.x; x[5]=b.y; x[6]=b.z; x[7]=b.w;
    } else if (l == 37){
        x[0]=er[296]; x[1]=er[297]; x[2]=er[298]; x[3]=er[299];
        x[4]=0.f; x[5]=0.f; x[6]=0.f; x[7]=0.f;
    } else {
        #pragma unroll
        for (int j = 0; j < 8; j++) x[j] = 0.f;
    }
    float nacc = 0.f;
    #pragma unroll
    for (int j = 0; j < 8; j++) nacc += x[j]*x[j];
    if (l < 40){
        half8 hv;
        #pragma unroll
        for (int j = 0; j < 8; j++) hv[j] = (_Float16)x[j];
        *(half8*)(sfg + r*KP + e0) = hv;
    }
    #pragma unroll
    for (int o = 32; o > 0; o >>= 1) nacc += __shfl_down(nacc, o);
    if (l == 0) ng[r] = nacc * vr;
}

// ---------------- mean over S of a fp16 [S,KP] tensor -> res segment --------
// grid (bc, 2), block 320
__global__ __launch_bounds__(320) void mean16_kernel(
    const _Float16* __restrict__ src1, const _Float16* __restrict__ src2,
    float* __restrict__ res, int b0, int seg){
    int bl = blockIdx.x, which = blockIdx.y;
    const _Float16* src = (which ? src2 : src1) + (size_t)bl*SS*KP;
    int e = threadIdx.x;
    if (e >= EE) return;
    float acc = 0.f;
    #pragma unroll 4
    for (int r = 0; r < SS; r++) acc += (float)src[r*KP + e];
    res[(size_t)(b0+bl)*FCIN + which*900 + seg*300 + e] = acc * (1.f/SS);
}

// ---------------- MFMA match (A-producing): stages sf16*v ----------------
// block 512 (8 waves); wave = 16 rows x 128 cols
__global__ __launch_bounds__(512, 4) void cross_matchA(
    const _Float16* __restrict__ sfA, const _Float16* __restrict__ sfB,
    const float* __restrict__ nAg, const float* __restrict__ nBg,
    const float* __restrict__ vAg, const float* __restrict__ vBg,
    _Float16* __restrict__ Ab16, _Float16* __restrict__ At16)
{
    __shared__ _Float16 As[128][40];
    __shared__ _Float16 Bs[128][40];
    __shared__ float nAl[128], nBl[128], vAl[128], vBl[128];

    int bl = blockIdx.x;
    int tid = threadIdx.x;
    int w = tid >> 6, lane = tid & 63;
    int m = lane & 15, quad = lane >> 4;

    const _Float16* gA = sfA + (size_t)bl*SS*KP;
    const _Float16* gB = sfB + (size_t)bl*SS*KP;

    if (tid < 128){ nAl[tid] = nAg[bl*SS + tid]; vAl[tid] = vAg[bl*SS + tid]; }
    else if (tid < 256){ nBl[tid-128] = nBg[bl*SS + tid-128]; vBl[tid-128] = vBg[bl*SS + tid-128]; }

    f32x4 acc[8];
    #pragma unroll
    for (int c = 0; c < 8; c++) acc[c] = (f32x4){0.f,0.f,0.f,0.f};

    int srow = tid >> 2, skq = (tid & 3) * 8;
    int arow = w*16 + m;

    for (int kc = 0; kc < 10; kc++){
        __syncthreads();
        {
            half8 ha = *(const half8*)(gA + srow*KP + kc*32 + skq);
            half8 hb = *(const half8*)(gB + srow*KP + kc*32 + skq);
            ha = ha * (_Float16)vAl[srow];
            hb = hb * (_Float16)vBl[srow];
            *(half8*)&As[srow][skq] = ha;
            *(half8*)&Bs[srow][skq] = hb;
        }
        __syncthreads();
        half8 a = *(const half8*)&As[arow][quad*8];
        #pragma unroll
        for (int c = 0; c < 8; c++){
            half8 b = *(const half8*)&Bs[c*16 + m][quad*8];
            acc[c] = __builtin_amdgcn_mfma_f32_16x16x32_f16(a, b, acc[c], 0, 0, 0);
        }
    }

    int ibase = w*16 + quad*4;
    _Float16* Ao  = Ab16 + (size_t)bl*SS*SS;
    _Float16* Ato = At16 + (size_t)bl*SS*SS;
    #pragma unroll
    for (int c = 0; c < 8; c++){
        int j = c*16 + m;
        float nc = nBl[j];
        #pragma unroll
        for (int r = 0; r < 4; r++){
            int i = ibase + r;
            float d2 = nAl[i] + nc - 2.f*acc[c][r];
            float d = sqrtf(fmaxf(d2, 0.f));
            _Float16 hv = (_Float16)(1.f / (1.f + d));
            Ao[i*SS + j]  = hv;
            Ato[j*SS + i] = hv;
        }
    }
}

// ---------------- MFMA match (sums only): stages o16*v, outputs w1/w2 --------
__global__ __launch_bounds__(512, 4) void cross_sums(
    const _Float16* __restrict__ oA, const _Float16* __restrict__ oB,
    const float* __restrict__ noA, const float* __restrict__ noB,
    const float* __restrict__ vAg, const float* __restrict__ vBg,
    float* __restrict__ w1g, float* __restrict__ w2g)
{
    __shared__ _Float16 As[128][40];
    __shared__ _Float16 Bs[128][40];
    __shared__ float nAl[128], nBl[128], vAl[128], vBl[128];
    __shared__ float colred[8][132];

    int bl = blockIdx.x;
    int tid = threadIdx.x;
    int w = tid >> 6, lane = tid & 63;
    int m = lane & 15, quad = lane >> 4;

    const _Float16* gA = oA + (size_t)bl*SS*KP;
    const _Float16* gB = oB + (size_t)bl*SS*KP;

    if (tid < 128){ nAl[tid] = noA[bl*SS + tid]; vAl[tid] = vAg[bl*SS + tid]; }
    else if (tid < 256){ nBl[tid-128] = noB[bl*SS + tid-128]; vBl[tid-128] = vBg[bl*SS + tid-128]; }

    f32x4 acc[8];
    #pragma unroll
    for (int c = 0; c < 8; c++) acc[c] = (f32x4){0.f,0.f,0.f,0.f};

    int srow = tid >> 2, skq = (tid & 3) * 8;
    int arow = w*16 + m;

    for (int kc = 0; kc < 10; kc++){
        __syncthreads();
        {
            half8 ha = *(const half8*)(gA + srow*KP + kc*32 + skq);
            half8 hb = *(const half8*)(gB + srow*KP + kc*32 + skq);
            ha = ha * (_Float16)vAl[srow];
            hb = hb * (_Float16)vBl[srow];
            *(half8*)&As[srow][skq] = ha;
            *(half8*)&Bs[srow][skq] = hb;
        }
        __syncthreads();
        half8 a = *(const half8*)&As[arow][quad*8];
        #pragma unroll
        for (int c = 0; c < 8; c++){
            half8 b = *(const half8*)&Bs[c*16 + m][quad*8];
            acc[c] = __builtin_amdgcn_mfma_f32_16x16x32_f16(a, b, acc[c], 0, 0, 0);
        }
    }

    int ibase = w*16 + quad*4;
    float aval[8][4];
    #pragma unroll
    for (int c = 0; c < 8; c++){
        float nc = nBl[c*16 + m];
        #pragma unroll
        for (int r = 0; r < 4; r++){
            float d2 = nAl[ibase+r] + nc - 2.f*acc[c][r];
            float d = sqrtf(fmaxf(d2, 0.f));
            aval[c][r] = 1.f / (1.f + d);
        }
    }

    float rp[4];
    #pragma unroll
    for (int r = 0; r < 4; r++){
        float s = 0.f;
        #pragma unroll
        for (int c = 0; c < 8; c++) s += aval[c][r];
        rp[r] = s;
    }
    #pragma unroll
    for (int mask = 1; mask < 16; mask <<= 1)
        #pragma unroll
        for (int r = 0; r < 4; r++) rp[r] += __shfl_xor(rp[r], mask);
    if (m == 0){
        #pragma unroll
        for (int r = 0; r < 4; r++) w1g[bl*SS + ibase + r] = rp[r];
    }
    float cp[8];
    #pragma unroll
    for (int c = 0; c < 8; c++){
        float s = 0.f;
        #pragma unroll
        for (int r = 0; r < 4; r++) s += aval[c][r];
        cp[c] = s;
    }
    #pragma unroll
    for (int c = 0; c < 8; c++){
        cp[c] += __shfl_xor(cp[c], 16);
        cp[c] += __shfl_xor(cp[c], 32);
    }
    if (quad == 0){
        #pragma unroll
        for (int c = 0; c < 8; c++) colred[w][c*16 + m] = cp[c];
    }
    __syncthreads();
    if (tid < 128){
        float s = 0.f;
        #pragma unroll
        for (int g = 0; g < 8; g++) s += colred[g][tid];
        w2g[bl*SS + tid] = s;
    }
}

// ---------------- f = Asrc @ W -> f16 (KP stride, zero pad) ----------------
// grid (bc, 4, 2); block 256; z: 0=Ab->f1, 1=At->f2
__global__ __launch_bounds__(256, 4) void f_mfma(
    const _Float16* __restrict__ Ab, const _Float16* __restrict__ At,
    const _Float16* __restrict__ Wt,
    _Float16* __restrict__ f1, _Float16* __restrict__ f2)
{
    __shared__ _Float16 Atile[128][136];
    int bl = blockIdx.x, es = blockIdx.y, zz = blockIdx.z;
    int e0 = es*80;
    int tid = threadIdx.x, w = tid >> 6, lane = tid & 63;
    int m = lane & 15, quad = lane >> 4;
    const _Float16* gA = (zz ? At : Ab) + (size_t)bl*SS*SS;
    #pragma unroll
    for (int u = 0; u < 8; u++){
        int idx = tid + u*256;
        int row = idx >> 4, jc = (idx & 15)*8;
        *(float4*)&Atile[row][jc] = *(const float4*)(gA + row*SS + jc);
    }
    __syncthreads();
    f32x4 acc[2][5];
    #pragma unroll
    for (int f = 0; f < 2; f++)
        #pragma unroll
        for (int c = 0; c < 5; c++) acc[f][c] = (f32x4){0.f,0.f,0.f,0.f};
    #pragma unroll
    for (int kc = 0; kc < 4; kc++){
        half8 a0 = *(const half8*)&Atile[w*32 + m][kc*32 + quad*8];
        half8 a1 = *(const half8*)&Atile[w*32 + 16 + m][kc*32 + quad*8];
        #pragma unroll
        for (int c = 0; c < 5; c++){
            int e = e0 + c*16 + m;
            half8 b = *(const half8*)(Wt + (size_t)e*SS + kc*32 + quad*8);
            acc[0][c] = __builtin_amdgcn_mfma_f32_16x16x32_f16(a0, b, acc[0][c], 0, 0, 0);
            acc[1][c] = __builtin_amdgcn_mfma_f32_16x16x32_f16(a1, b, acc[1][c], 0, 0, 0);
        }
    }
    _Float16* fo = (zz ? f2 : f1) + (size_t)bl*SS*KP;
    #pragma unroll
    for (int f = 0; f < 2; f++)
        #pragma unroll
        for (int c = 0; c < 5; c++){
            int e = e0 + c*16 + m;
            #pragma unroll
            for (int r = 0; r < 4; r++){
                int i = w*32 + f*16 + quad*4 + r;
                fo[(size_t)i*KP + e] = (e < EE) ? (_Float16)acc[f][c][r] : (_Float16)0.f;
            }
        }
}

// ---------------- conv(3x3,2ch fp16) + tanh -> o16 + masked norms ------------
// grid (bc, 32, 2), block 256 (4 waves, wave = 1 row); half8 + shfl halo
__global__ __launch_bounds__(256) void conv_kernel(
    const _Float16* __restrict__ sf1, const _Float16* __restrict__ sf2,
    const _Float16* __restrict__ f1, const _Float16* __restrict__ f2,
    const float* __restrict__ cw, const float* __restrict__ cb,
    _Float16* __restrict__ o16_1, _Float16* __restrict__ o16_2,
    float* __restrict__ no1, float* __restrict__ no2,
    const float* __restrict__ v1, const float* __restrict__ v2){
    int bl = blockIdx.x, which = blockIdx.z;
    int r = blockIdx.y*4 + (threadIdx.x >> 6);
    int l = threadIdx.x & 63;
    const _Float16* ca = (which ? sf2 : sf1) + (size_t)bl*SS*KP;
    const _Float16* cf = (which ? f2 : f1) + (size_t)bl*SS*KP;
    _Float16* od = (which ? o16_2 : o16_1) + (size_t)bl*SS*KP;
    float* nog = (which ? no2 : no1) + bl*SS;
    float vr = ((which ? v2 : v1) + bl*SS)[r];

    float wgt[2][3][3];
    #pragma unroll
    for (int c = 0; c < 2; c++)
        #pragma unroll
        for (int dy = 0; dy < 3; dy++)
            #pragma unroll
            for (int dx = 0; dx < 3; dx++)
                wgt[c][dy][dx] = cw[c*9 + dy*3 + dx];
    float bias = cb[0];

    int e0 = l*8;
    float acc[8];
    #pragma unroll
    for (int j = 0; j < 8; j++) acc[j] = bias;

    #pragma unroll
    for (int c = 0; c < 2; c++){
        const _Float16* src = c ? cf : ca;
        #pragma unroll
        for (int dy = 0; dy < 3; dy++){
            int gr = r + dy - 1;
            float xv[8];
            if (gr >= 0 && gr < SS && l < 40){
                half8 hv = *(const half8*)(src + gr*KP + e0);
                #pragma unroll
                for (int j = 0; j < 8; j++) xv[j] = (float)hv[j];
            } else {
                #pragma unroll
                for (int j = 0; j < 8; j++) xv[j] = 0.f;
            }
            float xm = __shfl_up(xv[7], 1); if (l == 0) xm = 0.f;
            float xp = __shfl_down(xv[0], 1);
            float w0 = wgt[c][dy][0], w1 = wgt[c][dy][1], w2 = wgt[c][dy][2];
            acc[0] = fmaf(w0, xm, fmaf(w1, xv[0], fmaf(w2, xv[1], acc[0])));
            #pragma unroll
            for (int j = 1; j < 7; j++)
                acc[j] = fmaf(w0, xv[j-1], fmaf(w1, xv[j], fmaf(w2, xv[j+1], acc[j])));
            acc[7] = fmaf(w0, xv[6], fmaf(w1, xv[7], fmaf(w2, xp, acc[7])));
        }
    }
    float nacc = 0.f;
    half8 outh;
    #pragma unroll
    for (int j = 0; j < 8; j++){
        int e = e0 + j;
        float t = (e < EE) ? fast_tanh(acc[j]) : 0.f;
        outh[j] = (_Float16)t;
        nacc += t*t;
    }
    if (l < 40) *(half8*)(od + r*KP + e0) = outh;
    #pragma unroll
    for (int o = 32; o > 0; o >>= 1) nacc += __shfl_down(nacc, o);
    if (l == 0) nog[r] = nacc * vr;
}

// ---------------- pool: sf16 += avg3(o16*w); masked norms --------------------
// grid (bc, 32, 2), block 256 (4 waves, wave = 1 row)
__global__ __launch_bounds__(256) void pool_kernel(
    const _Float16* __restrict__ o16_1, const _Float16* __restrict__ o16_2,
    const float* __restrict__ w1g, const float* __restrict__ w2g,
    const float* __restrict__ v1g, const float* __restrict__ v2g,
    _Float16* __restrict__ sf1, _Float16* __restrict__ sf2,
    float* __restrict__ n1, float* __restrict__ n2)
{
    int bl = blockIdx.x, which = blockIdx.z;
    int r = blockIdx.y*4 + (threadIdx.x >> 6);
    int l = threadIdx.x & 63;
    const _Float16* og = (which ? o16_2 : o16_1) + (size_t)bl*SS*KP;
    const float* wg = (which ? w2g : w1g) + bl*SS;
    float vr = ((which ? v2g : v1g) + bl*SS)[r];
    _Float16* sg = (which ? sf2 : sf1) + (size_t)bl*SS*KP;
    float* ng = (which ? n2 : n1) + bl*SS;

    float w0 = wg[r];
    float wm = (r > 0)   ? wg[r-1] : 0.f;
    float wp = (r < 127) ? wg[r+1] : 0.f;
    float nacc = 0.f;
    if (l < 40){
        int e0 = l*8;
        half8 o0 = *(const half8*)(og + r*KP + e0);
        half8 om = {};
        half8 op = {};
        if (r > 0)   om = *(const half8*)(og + (r-1)*KP + e0);
        if (r < 127) op = *(const half8*)(og + (r+1)*KP + e0);
        half8 sv = *(const half8*)(sg + r*KP + e0);
        half8 outh;
        #pragma unroll
        for (int j = 0; j < 8; j++){
            float a = (float)o0[j]*w0 + (float)om[j]*wm + (float)op[j]*wp;
            float ns = (float)sv[j] + a * (1.f/3.f);
            outh[j] = (_Float16)ns;
            float svv = ns * vr;
            nacc += svv*svv;
        }
        *(half8*)(sg + r*KP + e0) = outh;
    }
    #pragma unroll
    for (int o = 32; o > 0; o >>= 1) nacc += __shfl_down(nacc, o);
    if (l == 0) ng[r] = nacc;
}

// ---------------- fc1: [512,1800] @ [1800,300]^T ----------------
#define CKK 12
__global__ __launch_bounds__(256) void fc1_kernel(const float* __restrict__ res,
                                                  const float* __restrict__ fw,
                                                  const float* __restrict__ fb,
                                                  float* __restrict__ h){
    __shared__ float Xt[CKK][68];
    __shared__ float Wts[CKK][68];
    int bt = blockIdx.x, jt = blockIdx.y;
    int tid = threadIdx.x, tx = tid & 15, ty = tid >> 4;
    int b0l = bt*64, j0 = jt*64;
    float acc[4][4] = {};
    for (int k0 = 0; k0 < FCIN; k0 += CKK){
        #pragma unroll
        for (int u = 0; u < 3; u++){
            int idx = tid + u*256;
            int a = idx / CKK, k = idx - a*CKK;
            Xt[k][a] = res[(size_t)(b0l+a)*FCIN + k0 + k];
            int gj = j0 + a;
            Wts[k][a] = (gj < HH) ? fw[(size_t)gj*FCIN + k0 + k] : 0.f;
        }
        __syncthreads();
        #pragma unroll
        for (int k = 0; k < CKK; k++){
            float xv[4], wv[4];
            #pragma unroll
            for (int r = 0; r < 4; r++) xv[r] = Xt[k][ty*4+r];
            #pragma unroll
            for (int c = 0; c < 4; c++) wv[c] = Wts[k][tx*4+c];
            #pragma unroll
            for (int r = 0; r < 4; r++)
                #pragma unroll
                for (int c = 0; c < 4; c++)
                    acc[r][c] = fmaf(xv[r], wv[c], acc[r][c]);
        }
        __syncthreads();
    }
    #pragma unroll
    for (int r = 0; r < 4; r++){
        int gb = b0l + ty*4 + r;
        #pragma unroll
        for (int c = 0; c < 4; c++){
            int gj = j0 + tx*4 + c;
            if (gj < HH) h[(size_t)gb*HH + gj] = acc[r][c] + fb[gj];
        }
    }
}

// ---------------- layernorm + relu + fc2 + softmax ----------------
__global__ void head_kernel(const float* __restrict__ h, const float* __restrict__ g,
                            const float* __restrict__ be, const float* __restrict__ f2w,
                            const float* __restrict__ f2b, float* __restrict__ out){
    int b = blockIdx.x, tid = threadIdx.x;
    __shared__ float arr[HH];
    __shared__ float s_s[4], s_q[4], r0[4], r1[4];
    float x0 = (tid < HH) ? h[(size_t)b*HH + tid] : 0.f;
    float x1 = (tid + 256 < HH) ? h[(size_t)b*HH + tid + 256] : 0.f;
    float s = x0 + x1, sq = x0*x0 + x1*x1;
    #pragma unroll
    for (int o = 32; o > 0; o >>= 1){ s += __shfl_down(s, o); sq += __shfl_down(sq, o); }
    int wv = tid >> 6, ln = tid & 63;
    if (ln == 0){ s_s[wv] = s; s_q[wv] = sq; }
    __syncthreads();
    s  = s_s[0] + s_s[1] + s_s[2] + s_s[3];
    sq = s_q[0] + s_q[1] + s_q[2] + s_q[3];
    float mean = s / HH;
    float var = sq / HH - mean*mean;
    float inv = rsqrtf(var + 1e-5f);
    if (tid < HH)       arr[tid]     = fmaxf((x0 - mean)*inv*g[tid]     + be[tid],     0.f);
    if (tid + 256 < HH) arr[tid+256] = fmaxf((x1 - mean)*inv*g[tid+256] + be[tid+256], 0.f);
    __syncthreads();
    float p0 = 0.f, p1 = 0.f;
    for (int j = tid; j < HH; j += 256){ float hv = arr[j]; p0 += hv*f2w[j]; p1 += hv*f2w[HH+j]; }
    #pragma unroll
    for (int o = 32; o > 0; o >>= 1){ p0 += __shfl_down(p0, o); p1 += __shfl_down(p1, o); }
    if (ln == 0){ r0[wv] = p0; r1[wv] = p1; }
    __syncthreads();
    if (tid == 0){
        float o0 = r0[0]+r0[1]+r0[2]+r0[3] + f2b[0];
        float o1 = r1[0]+r1[1]+r1[2]+r1[3] + f2b[1];
        out[b*2+0] = o0; out[b*2+1] = o1;
        float m = fmaxf(o0, o1);
        float e0 = __expf(o0 - m), e1 = __expf(o1 - m);
        float den = e0 + e1;
        out[BB*2 + b*2+0] = e0/den;
        out[BB*2 + b*2+1] = e1/den;
    }
}

extern "C" void kernel_launch(void* const* d_in, const int* in_sizes, int n_in,
                              void* d_out, int out_size, void* d_ws, size_t ws_size,
                              hipStream_t stream){
    const int*   seq1   = (const int*)d_in[0];
    const int*   seq2   = (const int*)d_in[1];
    const float* emb    = (const float*)d_in[2];
    const float* W      = (const float*)d_in[3];
    const float* conv_w = (const float*)d_in[4];
    const float* conv_b = (const float*)d_in[5];
    const float* fc1_w  = (const float*)d_in[6];
    const float* fc1_b  = (const float*)d_in[7];
    const float* ln_g   = (const float*)d_in[8];
    const float* ln_b   = (const float*)d_in[9];
    const float* fc2_w  = (const float*)d_in[10];
    const float* fc2_b  = (const float*)d_in[11];
    float* out = (float*)d_out;

    float* ws = (float*)d_ws;
    size_t fixedf = (size_t)BB*FCIN + (size_t)BB*HH + (size_t)KP*SS;
    // per-batch floats: sf16 + o16 + f16 (each 2*SS*KP halves) + A/At + 8 vecs
    size_t perb = (size_t)3*SS*KP + (size_t)SS*SS + 8*SS;
    size_t avail = ws_size / 4;
    long long bcl = (long long)((avail > fixedf ? avail - fixedf : 0) / perb);
    int BC = (int)(bcl < 1 ? 1 : (bcl > BB ? BB : bcl));

    float* res = ws;
    float* hb  = res + (size_t)BB*FCIN;
    _Float16* Wt = (_Float16*)(hb + (size_t)BB*HH);
    _Float16* sf1 = Wt + (size_t)2*KP*SS;
    _Float16* sf2 = sf1 + (size_t)BC*SS*KP;
    _Float16* o16_1 = sf2 + (size_t)BC*SS*KP;
    _Float16* o16_2 = o16_1 + (size_t)BC*SS*KP;
    _Float16* f16_1 = o16_2 + (size_t)BC*SS*KP;
    _Float16* f16_2 = f16_1 + (size_t)BC*SS*KP;
    _Float16* Ab  = f16_2 + (size_t)BC*SS*KP;
    _Float16* At  = Ab  + (size_t)BC*SS*SS;
    float* n1  = (float*)(At + (size_t)BC*SS*SS);
    float* n2  = n1 + (size_t)BC*SS;
    float* no1 = n2 + (size_t)BC*SS;
    float* no2 = no1 + (size_t)BC*SS;
    float* w1  = no2 + (size_t)BC*SS;
    float* w2  = w1 + (size_t)BC*SS;
    float* v1  = w2 + (size_t)BC*SS;
    float* v2  = v1 + (size_t)BC*SS;

    wt_build_kernel<<<(2*KP*SS + 255)/256, 256, 0, stream>>>(W, Wt);

    for (int b0 = 0; b0 < BB; b0 += BC){
        int bc = (BB - b0 < BC) ? (BB - b0) : BC;
        embed_kernel<<<dim3(bc, 32, 2), 256, 0, stream>>>(seq1, seq2, emb, sf1, sf2,
                                                          v1, v2, n1, n2, b0);
        mean16_kernel<<<dim3(bc, 2), 320, 0, stream>>>(sf1, sf2, res, b0, 0);
        for (int it = 0; it < LLI; it++){
            cross_matchA<<<bc, 512, 0, stream>>>(sf1, sf2, n1, n2, v1, v2, Ab, At);
            f_mfma<<<dim3(bc, 4, 2), 256, 0, stream>>>(Ab, At, Wt + (size_t)it*KP*SS, f16_1, f16_2);
            conv_kernel<<<dim3(bc, 32, 2), 256, 0, stream>>>(sf1, sf2, f16_1, f16_2,
                                                             conv_w + it*18, conv_b + it,
                                                             o16_1, o16_2, no1, no2, v1, v2);
            mean16_kernel<<<dim3(bc, 2), 320, 0, stream>>>(o16_1, o16_2, res, b0, it+1);
            cross_sums<<<bc, 512, 0, stream>>>(o16_1, o16_2, no1, no2, v1, v2, w1, w2);
            pool_kernel<<<dim3(bc, 32, 2), 256, 0, stream>>>(o16_1, o16_2, w1, w2, v1, v2,
                                                             sf1, sf2, n1, n2);
        }
    }
    fc1_kernel<<<dim3(8, 5), 256, 0, stream>>>(res, fc1_w, fc1_b, hb);
    head_kernel<<<BB, 256, 0, stream>>>(hb, ln_g, ln_b, fc2_w, fc2_b, out);
}

// Round 8
// 857.811 us; speedup vs baseline: 4.7487x; 1.2750x over previous
//
#include <hip/hip_runtime.h>
#include <math.h>

#define BB 512
#define SS 128
#define EE 300
#define HH 300
#define FCIN 1800
#define LLI 2
#define KP 320          // padded K / leading dim for fp16 tensors

using half8 = __attribute__((ext_vector_type(8))) _Float16;
using f32x4 = __attribute__((ext_vector_type(4))) float;

__device__ __forceinline__ float fast_tanh(float x){
    float ax = fabsf(x);
    float t = __expf(-2.f*ax);
    float r = (1.f - t) / (1.f + t);
    return copysignf(r, x);
}

// ---------------- Wt build: Wt[it][e][j] = W[it][j][e], fp16, e zero-padded to 320
__global__ void wt_build_kernel(const float* __restrict__ W, _Float16* __restrict__ Wt){
    int idx = blockIdx.x*256 + threadIdx.x;      // 2*320*128 = 81920
    if (idx >= 2*KP*SS) return;
    int j = idx & 127;
    int e = (idx >> 7) % KP;
    int it = idx / (KP*SS);
    float v = (e < EE) ? W[(size_t)it*SS*EE + j*EE + e] : 0.f;
    Wt[idx] = (_Float16)v;
}

// ---------------- embed: gather -> sf16 (raw, KP-pad) + masked norms + v -----
// grid (bc, 32, 2), block 256 (4 waves, wave = 1 row)
__global__ __launch_bounds__(256) void embed_kernel(
    const int* __restrict__ seq1, const int* __restrict__ seq2,
    const float* __restrict__ emb,
    _Float16* __restrict__ sf1, _Float16* __restrict__ sf2,
    float* __restrict__ v1, float* __restrict__ v2,
    float* __restrict__ n1, float* __restrict__ n2, int b0){
    int bl = blockIdx.x, which = blockIdx.z;
    int r = blockIdx.y*4 + (threadIdx.x >> 6);
    int l = threadIdx.x & 63;
    const int* seq = which ? seq2 : seq1;
    _Float16* sfg = (which ? sf2 : sf1) + (size_t)bl*SS*KP;
    float* vd = (which ? v2 : v1) + bl*SS;
    float* ng = (which ? n2 : n1) + bl*SS;
    int token = seq[(size_t)(b0+bl)*SS + r];
    float vr = (token != 0) ? 1.f : 0.f;
    if (l == 0) vd[r] = vr;
    const float* er = emb + (size_t)token * EE;
    int e0 = l*8;
    float x[8];
    if (l < 37){
        float4 a = *(const float4*)(er + e0);
        float4 b = *(const float4*)(er + e0 + 4);
        x[0]=a.x; x[1]=a.y; x[2]=a.z; x[3]=a.w;
        x[4]=b.x; x[5]=b.y; x[6]=b.z; x[7]=b.w;
    } else if (l == 37){
        x[0]=er[296]; x[1]=er[297]; x[2]=er[298]; x[3]=er[299];
        x[4]=0.f; x[5]=0.f; x[6]=0.f; x[7]=0.f;
    } else {
        #pragma unroll
        for (int j = 0; j < 8; j++) x[j] = 0.f;
    }
    float nacc = 0.f;
    #pragma unroll
    for (int j = 0; j < 8; j++) nacc += x[j]*x[j];
    if (l < 40){
        half8 hv;
        #pragma unroll
        for (int j = 0; j < 8; j++) hv[j] = (_Float16)x[j];
        *(half8*)(sfg + r*KP + e0) = hv;
    }
    #pragma unroll
    for (int o = 32; o > 0; o >>= 1) nacc += __shfl_down(nacc, o);
    if (l == 0) ng[r] = nacc * vr;
}

// ---------------- mean over S of a fp16 [S,KP] tensor -> res segment --------
// grid (bc, 2), block 320
__global__ __launch_bounds__(320) void mean16_kernel(
    const _Float16* __restrict__ src1, const _Float16* __restrict__ src2,
    float* __restrict__ res, int b0, int seg){
    int bl = blockIdx.x, which = blockIdx.y;
    const _Float16* src = (which ? src2 : src1) + (size_t)bl*SS*KP;
    int e = threadIdx.x;
    if (e >= EE) return;
    float acc = 0.f;
    #pragma unroll 4
    for (int r = 0; r < SS; r++) acc += (float)src[r*KP + e];
    res[(size_t)(b0+bl)*FCIN + which*900 + seg*300 + e] = acc * (1.f/SS);
}

// ---------------- MFMA match (A-producing): stages sf16*v -> Ab only ---------
// block 512 (8 waves); wave = 16 rows x 128 cols
__global__ __launch_bounds__(512, 4) void cross_matchA(
    const _Float16* __restrict__ sfA, const _Float16* __restrict__ sfB,
    const float* __restrict__ nAg, const float* __restrict__ nBg,
    const float* __restrict__ vAg, const float* __restrict__ vBg,
    _Float16* __restrict__ Ab16)
{
    __shared__ _Float16 As[128][40];
    __shared__ _Float16 Bs[128][40];
    __shared__ float nAl[128], nBl[128], vAl[128], vBl[128];

    int bl = blockIdx.x;
    int tid = threadIdx.x;
    int w = tid >> 6, lane = tid & 63;
    int m = lane & 15, quad = lane >> 4;

    const _Float16* gA = sfA + (size_t)bl*SS*KP;
    const _Float16* gB = sfB + (size_t)bl*SS*KP;

    if (tid < 128){ nAl[tid] = nAg[bl*SS + tid]; vAl[tid] = vAg[bl*SS + tid]; }
    else if (tid < 256){ nBl[tid-128] = nBg[bl*SS + tid-128]; vBl[tid-128] = vBg[bl*SS + tid-128]; }

    f32x4 acc[8];
    #pragma unroll
    for (int c = 0; c < 8; c++) acc[c] = (f32x4){0.f,0.f,0.f,0.f};

    int srow = tid >> 2, skq = (tid & 3) * 8;
    int arow = w*16 + m;

    for (int kc = 0; kc < 10; kc++){
        __syncthreads();
        {
            half8 ha = *(const half8*)(gA + srow*KP + kc*32 + skq);
            half8 hb = *(const half8*)(gB + srow*KP + kc*32 + skq);
            ha = ha * (_Float16)vAl[srow];
            hb = hb * (_Float16)vBl[srow];
            *(half8*)&As[srow][skq] = ha;
            *(half8*)&Bs[srow][skq] = hb;
        }
        __syncthreads();
        half8 a = *(const half8*)&As[arow][quad*8];
        #pragma unroll
        for (int c = 0; c < 8; c++){
            half8 b = *(const half8*)&Bs[c*16 + m][quad*8];
            acc[c] = __builtin_amdgcn_mfma_f32_16x16x32_f16(a, b, acc[c], 0, 0, 0);
        }
    }

    int ibase = w*16 + quad*4;
    _Float16* Ao = Ab16 + (size_t)bl*SS*SS;
    #pragma unroll
    for (int c = 0; c < 8; c++){
        int j = c*16 + m;
        float nc = nBl[j];
        #pragma unroll
        for (int r = 0; r < 4; r++){
            int i = ibase + r;
            float d2 = nAl[i] + nc - 2.f*acc[c][r];
            float d = sqrtf(fmaxf(d2, 0.f));
            Ao[i*SS + j] = (_Float16)(1.f / (1.f + d));
        }
    }
}

// ---------------- MFMA match sums + fused pool/residual/norms ----------------
// block 512; after w1/w2 (LDS), parallel epilogue: sf += avg3(o*w), norms
__global__ __launch_bounds__(512, 4) void cross_sums_pool(
    const _Float16* __restrict__ oA, const _Float16* __restrict__ oB,
    const float* __restrict__ noA, const float* __restrict__ noB,
    const float* __restrict__ vAg, const float* __restrict__ vBg,
    _Float16* __restrict__ sf1, _Float16* __restrict__ sf2,
    float* __restrict__ n1, float* __restrict__ n2)
{
    __shared__ _Float16 As[128][40];
    __shared__ _Float16 Bs[128][40];
    __shared__ float nAl[128], nBl[128], vAl[128], vBl[128];
    __shared__ float colred[8][132];
    __shared__ float wr[128], wc[128];

    int bl = blockIdx.x;
    int tid = threadIdx.x;
    int w = tid >> 6, lane = tid & 63;
    int m = lane & 15, quad = lane >> 4;

    const _Float16* gA = oA + (size_t)bl*SS*KP;
    const _Float16* gB = oB + (size_t)bl*SS*KP;

    if (tid < 128){ nAl[tid] = noA[bl*SS + tid]; vAl[tid] = vAg[bl*SS + tid]; }
    else if (tid < 256){ nBl[tid-128] = noB[bl*SS + tid-128]; vBl[tid-128] = vBg[bl*SS + tid-128]; }

    f32x4 acc[8];
    #pragma unroll
    for (int c = 0; c < 8; c++) acc[c] = (f32x4){0.f,0.f,0.f,0.f};

    int srow = tid >> 2, skq = (tid & 3) * 8;
    int arow = w*16 + m;

    for (int kc = 0; kc < 10; kc++){
        __syncthreads();
        {
            half8 ha = *(const half8*)(gA + srow*KP + kc*32 + skq);
            half8 hb = *(const half8*)(gB + srow*KP + kc*32 + skq);
            ha = ha * (_Float16)vAl[srow];
            hb = hb * (_Float16)vBl[srow];
            *(half8*)&As[srow][skq] = ha;
            *(half8*)&Bs[srow][skq] = hb;
        }
        __syncthreads();
        half8 a = *(const half8*)&As[arow][quad*8];
        #pragma unroll
        for (int c = 0; c < 8; c++){
            half8 b = *(const half8*)&Bs[c*16 + m][quad*8];
            acc[c] = __builtin_amdgcn_mfma_f32_16x16x32_f16(a, b, acc[c], 0, 0, 0);
        }
    }

    int ibase = w*16 + quad*4;
    float aval[8][4];
    #pragma unroll
    for (int c = 0; c < 8; c++){
        float nc = nBl[c*16 + m];
        #pragma unroll
        for (int r = 0; r < 4; r++){
            float d2 = nAl[ibase+r] + nc - 2.f*acc[c][r];
            float d = sqrtf(fmaxf(d2, 0.f));
            aval[c][r] = 1.f / (1.f + d);
        }
    }

    // row sums -> wr
    float rp[4];
    #pragma unroll
    for (int r = 0; r < 4; r++){
        float s = 0.f;
        #pragma unroll
        for (int c = 0; c < 8; c++) s += aval[c][r];
        rp[r] = s;
    }
    #pragma unroll
    for (int mask = 1; mask < 16; mask <<= 1)
        #pragma unroll
        for (int r = 0; r < 4; r++) rp[r] += __shfl_xor(rp[r], mask);
    if (m == 0){
        #pragma unroll
        for (int r = 0; r < 4; r++) wr[ibase + r] = rp[r];
    }
    // col sums -> wc
    float cp[8];
    #pragma unroll
    for (int c = 0; c < 8; c++){
        float s = 0.f;
        #pragma unroll
        for (int r = 0; r < 4; r++) s += aval[c][r];
        cp[c] = s;
    }
    #pragma unroll
    for (int c = 0; c < 8; c++){
        cp[c] += __shfl_xor(cp[c], 16);
        cp[c] += __shfl_xor(cp[c], 32);
    }
    if (quad == 0){
        #pragma unroll
        for (int c = 0; c < 8; c++) colred[w][c*16 + m] = cp[c];
    }
    __syncthreads();
    if (tid < 128){
        float s = 0.f;
        #pragma unroll
        for (int g = 0; g < 8; g++) s += colred[g][tid];
        wc[tid] = s;
    }
    __syncthreads();

    // ---- fused pool epilogue: 4 lanes per row (tid>>2 = row, tid&3 = sub) ----
    int prow = tid >> 2, sub = tid & 3;
    #pragma unroll
    for (int which = 0; which < 2; which++){
        const _Float16* og = which ? gB : gA;
        const float* wv = which ? wc : wr;
        _Float16* sg = (which ? sf2 : sf1) + (size_t)bl*SS*KP;
        float* ng = (which ? n2 : n1) + bl*SS;
        float vr = which ? vBl[prow] : vAl[prow];
        float w0 = wv[prow];
        float wm = (prow > 0)   ? wv[prow-1] : 0.f;
        float wp = (prow < 127) ? wv[prow+1] : 0.f;
        float nacc = 0.f;
        #pragma unroll
        for (int k = 0; k < 10; k++){
            int e0 = (sub + k*4) * 8;           // < 320
            half8 o0 = *(const half8*)(og + prow*KP + e0);
            half8 om = {};
            half8 op = {};
            if (prow > 0)   om = *(const half8*)(og + (prow-1)*KP + e0);
            if (prow < 127) op = *(const half8*)(og + (prow+1)*KP + e0);
            half8 sv = *(const half8*)(sg + prow*KP + e0);
            half8 outh;
            #pragma unroll
            for (int j = 0; j < 8; j++){
                float a = (float)o0[j]*w0 + (float)om[j]*wm + (float)op[j]*wp;
                float ns = (float)sv[j] + a * (1.f/3.f);
                outh[j] = (_Float16)ns;
                float svv = ns * vr;
                nacc += svv*svv;
            }
            *(half8*)(sg + prow*KP + e0) = outh;
        }
        nacc += __shfl_xor(nacc, 1);
        nacc += __shfl_xor(nacc, 2);
        if (sub == 0) ng[prow] = nacc;
    }
}

// ---------------- f = A@W (zz=0) or A^T@W (zz=1, LDS transpose) -> f16 -------
// grid (bc, 4, 2); block 256
__global__ __launch_bounds__(256, 4) void f_mfma(
    const _Float16* __restrict__ Ab, const _Float16* __restrict__ Wt,
    _Float16* __restrict__ f1, _Float16* __restrict__ f2)
{
    __shared__ _Float16 Atile[128][136];
    int bl = blockIdx.x, es = blockIdx.y, zz = blockIdx.z;
    int e0 = es*80;
    int tid = threadIdx.x, w = tid >> 6, lane = tid & 63;
    int m = lane & 15, quad = lane >> 4;
    const _Float16* gA = Ab + (size_t)bl*SS*SS;
    if (zz == 0){
        #pragma unroll
        for (int u = 0; u < 8; u++){
            int idx = tid + u*256;
            int row = idx >> 4, jc = (idx & 15)*8;
            *(float4*)&Atile[row][jc] = *(const float4*)(gA + row*SS + jc);
        }
    } else {
        #pragma unroll
        for (int u = 0; u < 8; u++){
            int idx = tid + u*256;
            int row = idx >> 4, jc = (idx & 15)*8;
            half8 hv = *(const half8*)(gA + row*SS + jc);
            #pragma unroll
            for (int j = 0; j < 8; j++) Atile[jc+j][row] = hv[j];
        }
    }
    __syncthreads();
    f32x4 acc[2][5];
    #pragma unroll
    for (int f = 0; f < 2; f++)
        #pragma unroll
        for (int c = 0; c < 5; c++) acc[f][c] = (f32x4){0.f,0.f,0.f,0.f};
    #pragma unroll
    for (int kc = 0; kc < 4; kc++){
        half8 a0 = *(const half8*)&Atile[w*32 + m][kc*32 + quad*8];
        half8 a1 = *(const half8*)&Atile[w*32 + 16 + m][kc*32 + quad*8];
        #pragma unroll
        for (int c = 0; c < 5; c++){
            int e = e0 + c*16 + m;
            half8 b = *(const half8*)(Wt + (size_t)e*SS + kc*32 + quad*8);
            acc[0][c] = __builtin_amdgcn_mfma_f32_16x16x32_f16(a0, b, acc[0][c], 0, 0, 0);
            acc[1][c] = __builtin_amdgcn_mfma_f32_16x16x32_f16(a1, b, acc[1][c], 0, 0, 0);
        }
    }
    _Float16* fo = (zz ? f2 : f1) + (size_t)bl*SS*KP;
    #pragma unroll
    for (int f = 0; f < 2; f++)
        #pragma unroll
        for (int c = 0; c < 5; c++){
            int e = e0 + c*16 + m;
            #pragma unroll
            for (int r = 0; r < 4; r++){
                int i = w*32 + f*16 + quad*4 + r;
                fo[(size_t)i*KP + e] = (e < EE) ? (_Float16)acc[f][c][r] : (_Float16)0.f;
            }
        }
}

// ---------------- conv(3x3,2ch fp16) + tanh -> o16 + masked norms ------------
// grid (bc, 32, 2), block 256 (4 waves, wave = 1 row); half8 + shfl halo
__global__ __launch_bounds__(256) void conv_kernel(
    const _Float16* __restrict__ sf1, const _Float16* __restrict__ sf2,
    const _Float16* __restrict__ f1, const _Float16* __restrict__ f2,
    const float* __restrict__ cw, const float* __restrict__ cb,
    _Float16* __restrict__ o16_1, _Float16* __restrict__ o16_2,
    float* __restrict__ no1, float* __restrict__ no2,
    const float* __restrict__ v1, const float* __restrict__ v2){
    int bl = blockIdx.x, which = blockIdx.z;
    int r = blockIdx.y*4 + (threadIdx.x >> 6);
    int l = threadIdx.x & 63;
    const _Float16* ca = (which ? sf2 : sf1) + (size_t)bl*SS*KP;
    const _Float16* cf = (which ? f2 : f1) + (size_t)bl*SS*KP;
    _Float16* od = (which ? o16_2 : o16_1) + (size_t)bl*SS*KP;
    float* nog = (which ? no2 : no1) + bl*SS;
    float vr = ((which ? v2 : v1) + bl*SS)[r];

    float wgt[2][3][3];
    #pragma unroll
    for (int c = 0; c < 2; c++)
        #pragma unroll
        for (int dy = 0; dy < 3; dy++)
            #pragma unroll
            for (int dx = 0; dx < 3; dx++)
                wgt[c][dy][dx] = cw[c*9 + dy*3 + dx];
    float bias = cb[0];

    int e0 = l*8;
    float acc[8];
    #pragma unroll
    for (int j = 0; j < 8; j++) acc[j] = bias;

    #pragma unroll
    for (int c = 0; c < 2; c++){
        const _Float16* src = c ? cf : ca;
        #pragma unroll
        for (int dy = 0; dy < 3; dy++){
            int gr = r + dy - 1;
            float xv[8];
            if (gr >= 0 && gr < SS && l < 40){
                half8 hv = *(const half8*)(src + gr*KP + e0);
                #pragma unroll
                for (int j = 0; j < 8; j++) xv[j] = (float)hv[j];
            } else {
                #pragma unroll
                for (int j = 0; j < 8; j++) xv[j] = 0.f;
            }
            float xm = __shfl_up(xv[7], 1); if (l == 0) xm = 0.f;
            float xp = __shfl_down(xv[0], 1);
            float w0 = wgt[c][dy][0], w1 = wgt[c][dy][1], w2 = wgt[c][dy][2];
            acc[0] = fmaf(w0, xm, fmaf(w1, xv[0], fmaf(w2, xv[1], acc[0])));
            #pragma unroll
            for (int j = 1; j < 7; j++)
                acc[j] = fmaf(w0, xv[j-1], fmaf(w1, xv[j], fmaf(w2, xv[j+1], acc[j])));
            acc[7] = fmaf(w0, xv[6], fmaf(w1, xv[7], fmaf(w2, xp, acc[7])));
        }
    }
    float nacc = 0.f;
    half8 outh;
    #pragma unroll
    for (int j = 0; j < 8; j++){
        int e = e0 + j;
        float t = (e < EE) ? fast_tanh(acc[j]) : 0.f;
        outh[j] = (_Float16)t;
        nacc += t*t;
    }
    if (l < 40) *(half8*)(od + r*KP + e0) = outh;
    #pragma unroll
    for (int o = 32; o > 0; o >>= 1) nacc += __shfl_down(nacc, o);
    if (l == 0) nog[r] = nacc * vr;
}

// ---------------- fc1: K-split x6, atomic accumulate into h ------------------
// grid (8,5,6), block 256; h must be zeroed before launch
#define CKK 12
__global__ __launch_bounds__(256) void fc1_kernel(const float* __restrict__ res,
                                                  const float* __restrict__ fw,
                                                  float* __restrict__ h){
    __shared__ float Xt[CKK][68];
    __shared__ float Wts[CKK][68];
    int bt = blockIdx.x, jt = blockIdx.y, kz = blockIdx.z;
    int tid = threadIdx.x, tx = tid & 15, ty = tid >> 4;
    int b0l = bt*64, j0 = jt*64, kbase = kz*300;
    float acc[4][4] = {};
    for (int k0 = 0; k0 < 300; k0 += CKK){
        #pragma unroll
        for (int u = 0; u < 3; u++){
            int idx = tid + u*256;
            int a = idx / CKK, k = idx - a*CKK;
            Xt[k][a] = res[(size_t)(b0l+a)*FCIN + kbase + k0 + k];
            int gj = j0 + a;
            Wts[k][a] = (gj < HH) ? fw[(size_t)gj*FCIN + kbase + k0 + k] : 0.f;
        }
        __syncthreads();
        #pragma unroll
        for (int k = 0; k < CKK; k++){
            float xv[4], wv[4];
            #pragma unroll
            for (int r = 0; r < 4; r++) xv[r] = Xt[k][ty*4+r];
            #pragma unroll
            for (int c = 0; c < 4; c++) wv[c] = Wts[k][tx*4+c];
            #pragma unroll
            for (int r = 0; r < 4; r++)
                #pragma unroll
                for (int c = 0; c < 4; c++)
                    acc[r][c] = fmaf(xv[r], wv[c], acc[r][c]);
        }
        __syncthreads();
    }
    #pragma unroll
    for (int r = 0; r < 4; r++){
        int gb = b0l + ty*4 + r;
        #pragma unroll
        for (int c = 0; c < 4; c++){
            int gj = j0 + tx*4 + c;
            if (gj < HH) atomicAdd(&h[(size_t)gb*HH + gj], acc[r][c]);
        }
    }
}

// ---------------- layernorm + relu + fc2 + softmax (+fc1 bias) ---------------
__global__ void head_kernel(const float* __restrict__ h, const float* __restrict__ fb,
                            const float* __restrict__ g,
                            const float* __restrict__ be, const float* __restrict__ f2w,
                            const float* __restrict__ f2b, float* __restrict__ out){
    int b = blockIdx.x, tid = threadIdx.x;
    __shared__ float arr[HH];
    __shared__ float s_s[4], s_q[4], r0[4], r1[4];
    float x0 = (tid < HH) ? h[(size_t)b*HH + tid] + fb[tid] : 0.f;
    float x1 = (tid + 256 < HH) ? h[(size_t)b*HH + tid + 256] + fb[tid+256] : 0.f;
    float s = x0 + x1, sq = x0*x0 + x1*x1;
    #pragma unroll
    for (int o = 32; o > 0; o >>= 1){ s += __shfl_down(s, o); sq += __shfl_down(sq, o); }
    int wv = tid >> 6, ln = tid & 63;
    if (ln == 0){ s_s[wv] = s; s_q[wv] = sq; }
    __syncthreads();
    s  = s_s[0] + s_s[1] + s_s[2] + s_s[3];
    sq = s_q[0] + s_q[1] + s_q[2] + s_q[3];
    float mean = s / HH;
    float var = sq / HH - mean*mean;
    float inv = rsqrtf(var + 1e-5f);
    if (tid < HH)       arr[tid]     = fmaxf((x0 - mean)*inv*g[tid]     + be[tid],     0.f);
    if (tid + 256 < HH) arr[tid+256] = fmaxf((x1 - mean)*inv*g[tid+256] + be[tid+256], 0.f);
    __syncthreads();
    float p0 = 0.f, p1 = 0.f;
    for (int j = tid; j < HH; j += 256){ float hv = arr[j]; p0 += hv*f2w[j]; p1 += hv*f2w[HH+j]; }
    #pragma unroll
    for (int o = 32; o > 0; o >>= 1){ p0 += __shfl_down(p0, o); p1 += __shfl_down(p1, o); }
    if (ln == 0){ r0[wv] = p0; r1[wv] = p1; }
    __syncthreads();
    if (tid == 0){
        float o0 = r0[0]+r0[1]+r0[2]+r0[3] + f2b[0];
        float o1 = r1[0]+r1[1]+r1[2]+r1[3] + f2b[1];
        out[b*2+0] = o0; out[b*2+1] = o1;
        float m = fmaxf(o0, o1);
        float e0 = __expf(o0 - m), e1 = __expf(o1 - m);
        float den = e0 + e1;
        out[BB*2 + b*2+0] = e0/den;
        out[BB*2 + b*2+1] = e1/den;
    }
}

extern "C" void kernel_launch(void* const* d_in, const int* in_sizes, int n_in,
                              void* d_out, int out_size, void* d_ws, size_t ws_size,
                              hipStream_t stream){
    const int*   seq1   = (const int*)d_in[0];
    const int*   seq2   = (const int*)d_in[1];
    const float* emb    = (const float*)d_in[2];
    const float* W      = (const float*)d_in[3];
    const float* conv_w = (const float*)d_in[4];
    const float* conv_b = (const float*)d_in[5];
    const float* fc1_w  = (const float*)d_in[6];
    const float* fc1_b  = (const float*)d_in[7];
    const float* ln_g   = (const float*)d_in[8];
    const float* ln_b   = (const float*)d_in[9];
    const float* fc2_w  = (const float*)d_in[10];
    const float* fc2_b  = (const float*)d_in[11];
    float* out = (float*)d_out;

    float* ws = (float*)d_ws;
    size_t fixedf = (size_t)BB*FCIN + (size_t)BB*HH + (size_t)KP*SS;
    // per-batch floats: sf16 + o16 + f16 (each 2*SS*KP halves) + A + 6 vecs
    size_t perb = (size_t)3*SS*KP + (size_t)(SS*SS/2) + 6*SS;
    size_t avail = ws_size / 4;
    long long bcl = (long long)((avail > fixedf ? avail - fixedf : 0) / perb);
    int BC = (int)(bcl < 1 ? 1 : (bcl > BB ? BB : bcl));

    float* res = ws;
    float* hb  = res + (size_t)BB*FCIN;
    _Float16* Wt = (_Float16*)(hb + (size_t)BB*HH);
    _Float16* sf1 = Wt + (size_t)2*KP*SS;
    _Float16* sf2 = sf1 + (size_t)BC*SS*KP;
    _Float16* o16_1 = sf2 + (size_t)BC*SS*KP;
    _Float16* o16_2 = o16_1 + (size_t)BC*SS*KP;
    _Float16* f16_1 = o16_2 + (size_t)BC*SS*KP;
    _Float16* f16_2 = f16_1 + (size_t)BC*SS*KP;
    _Float16* Ab  = f16_2 + (size_t)BC*SS*KP;
    float* n1  = (float*)(Ab + (size_t)BC*SS*SS);
    float* n2  = n1 + (size_t)BC*SS;
    float* no1 = n2 + (size_t)BC*SS;
    float* no2 = no1 + (size_t)BC*SS;
    float* v1  = no2 + (size_t)BC*SS;
    float* v2  = v1 + (size_t)BC*SS;

    wt_build_kernel<<<(2*KP*SS + 255)/256, 256, 0, stream>>>(W, Wt);
    hipMemsetAsync(hb, 0, (size_t)BB*HH*sizeof(float), stream);

    for (int b0 = 0; b0 < BB; b0 += BC){
        int bc = (BB - b0 < BC) ? (BB - b0) : BC;
        embed_kernel<<<dim3(bc, 32, 2), 256, 0, stream>>>(seq1, seq2, emb, sf1, sf2,
                                                          v1, v2, n1, n2, b0);
        mean16_kernel<<<dim3(bc, 2), 320, 0, stream>>>(sf1, sf2, res, b0, 0);
        for (int it = 0; it < LLI; it++){
            cross_matchA<<<bc, 512, 0, stream>>>(sf1, sf2, n1, n2, v1, v2, Ab);
            f_mfma<<<dim3(bc, 4, 2), 256, 0, stream>>>(Ab, Wt + (size_t)it*KP*SS, f16_1, f16_2);
            conv_kernel<<<dim3(bc, 32, 2), 256, 0, stream>>>(sf1, sf2, f16_1, f16_2,
                                                             conv_w + it*18, conv_b + it,
                                                             o16_1, o16_2, no1, no2, v1, v2);
            mean16_kernel<<<dim3(bc, 2), 320, 0, stream>>>(o16_1, o16_2, res, b0, it+1);
            cross_sums_pool<<<bc, 512, 0, stream>>>(o16_1, o16_2, no1, no2, v1, v2,
                                                    sf1, sf2, n1, n2);
        }
    }
    fc1_kernel<<<dim3(8, 5, 6), 256, 0, stream>>>(res, fc1_w, hb);
    head_kernel<<<BB, 256, 0, stream>>>(hb, fc1_b, ln_g, ln_b, fc2_w, fc2_b, out);
}